// Round 1
// baseline (3905.840 us; speedup 1.0000x reference)
//
#include <hip/hip_runtime.h>
#include <hip/hip_bf16.h>
#include <math.h>

#define N_NODES 100000
#define N_EDGES 1600000

// ---------------- degree ----------------
__global__ __launch_bounds__(256) void k_deg(const int* __restrict__ tgt,
                                             float* __restrict__ deg) {
    int e = blockIdx.x * 256 + threadIdx.x;
    if (e < N_EDGES) atomicAdd(&deg[tgt[e]], 1.0f);
}

// ------------- scatter-add: one thread per (edge, 4 features) -------------
// D = 64 -> 16 threads/edge ; D = 32 -> 8 threads/edge. Exact grids.
template <int D>
__global__ __launch_bounds__(256) void k_scatter(const float* __restrict__ x,
                                                 const int* __restrict__ ei,
                                                 float* __restrict__ msg) {
    constexpr int TPE = D / 4;
    unsigned gid = blockIdx.x * 256u + threadIdx.x;
    unsigned e = gid / TPE;
    unsigned q = gid % TPE;
    int s = ei[e];            // src
    int t = ei[N_EDGES + e];  // tgt
    float4 v = *reinterpret_cast<const float4*>(x + (size_t)s * D + q * 4);
    float* m = msg + (size_t)t * D + q * 4;
    atomicAdd(m + 0, v.x);
    atomicAdd(m + 1, v.y);
    atomicAdd(m + 2, v.z);
    atomicAdd(m + 3, v.w);
}

// ------------- SAGE transform, DIN=64, DOUT=64 -------------
// out[n] = normalize( (msg[n]/max(deg,1)) @ Wl + b + x[n] @ Wr ), opt ReLU.
// 32 nodes per block (8 iters of 4 nodes). Weights staged in LDS.
template <bool RELU>
__global__ __launch_bounds__(256) void k_sage64(const float* __restrict__ x,
                                                const float* __restrict__ msg,
                                                const float* __restrict__ deg,
                                                const float* __restrict__ Wl,
                                                const float* __restrict__ b,
                                                const float* __restrict__ Wr,
                                                float* __restrict__ out) {
    __shared__ float sWl[4096], sWr[4096];
    __shared__ float sA[4][64], sX[4][64];
    int t = threadIdx.x;
    for (int i = t; i < 4096; i += 256) { sWl[i] = Wl[i]; sWr[i] = Wr[i]; }
    int ln = t >> 6, o = t & 63;
    for (int it = 0; it < 8; ++it) {
        int node = blockIdx.x * 32 + it * 4 + ln;
        __syncthreads();  // weights ready (it=0) / previous iter done reading
        float invd = 1.0f / fmaxf(deg[node], 1.0f);
        sA[ln][o] = msg[(size_t)node * 64 + o] * invd;
        sX[ln][o] = x[(size_t)node * 64 + o];
        __syncthreads();
        float acc = b[o];
#pragma unroll
        for (int f = 0; f < 64; ++f)
            acc += sA[ln][f] * sWl[f * 64 + o] + sX[ln][f] * sWr[f * 64 + o];
        float ss = acc * acc;
#pragma unroll
        for (int m = 32; m; m >>= 1) ss += __shfl_xor(ss, m);
        float v = acc / fmaxf(sqrtf(ss), 1e-12f);
        if (RELU) v = fmaxf(v, 0.0f);
        out[(size_t)node * 64 + o] = v;
    }
}

// ------------- pre-transform layer3: z = x @ W3l  (64 -> 32) -------------
__global__ __launch_bounds__(256) void k_pretrans(const float* __restrict__ x,
                                                  const float* __restrict__ W,
                                                  float* __restrict__ z) {
    __shared__ float sW[2048];
    __shared__ float sX[8][64];
    int t = threadIdx.x;
    for (int i = t; i < 2048; i += 256) sW[i] = W[i];
    int ln = t >> 5, o = t & 31;
    for (int it = 0; it < 8; ++it) {
        int node = blockIdx.x * 64 + it * 8 + ln;
        __syncthreads();
        if (node < N_NODES) {
            sX[ln][o] = x[(size_t)node * 64 + o];
            sX[ln][o + 32] = x[(size_t)node * 64 + o + 32];
        }
        __syncthreads();
        if (node < N_NODES) {
            float acc = 0.0f;
#pragma unroll
            for (int f = 0; f < 64; ++f) acc += sX[ln][f] * sW[f * 32 + o];
            z[(size_t)node * 32 + o] = acc;
        }
    }
}

// ------------- layer3 finalize -------------
// out[n] = normalize( msg32[n]/max(deg,1) + b3 + x[n] @ W3r ), x = h2 [N,64]
__global__ __launch_bounds__(256) void k_fin3(const float* __restrict__ x,
                                              const float* __restrict__ msg32,
                                              const float* __restrict__ deg,
                                              const float* __restrict__ b,
                                              const float* __restrict__ Wr,
                                              float* __restrict__ out) {
    __shared__ float sW[2048];
    __shared__ float sX[8][64];
    int t = threadIdx.x;
    for (int i = t; i < 2048; i += 256) sW[i] = Wr[i];
    int ln = t >> 5, o = t & 31;
    for (int it = 0; it < 8; ++it) {
        int node = blockIdx.x * 64 + it * 8 + ln;
        __syncthreads();
        if (node < N_NODES) {
            sX[ln][o] = x[(size_t)node * 64 + o];
            sX[ln][o + 32] = x[(size_t)node * 64 + o + 32];
        }
        __syncthreads();
        if (node < N_NODES) {
            float invd = 1.0f / fmaxf(deg[node], 1.0f);
            float acc = msg32[(size_t)node * 32 + o] * invd + b[o];
#pragma unroll
            for (int f = 0; f < 64; ++f) acc += sX[ln][f] * sW[f * 32 + o];
            float ss = acc * acc;
#pragma unroll
            for (int m = 16; m; m >>= 1) ss += __shfl_xor(ss, m);
            out[(size_t)node * 32 + o] = acc / fmaxf(sqrtf(ss), 1e-12f);
        }
    }
}

// ------------- column sum of h3 [N,32] -------------
__global__ __launch_bounds__(256) void k_colsum(const float* __restrict__ h,
                                                float* __restrict__ colsum) {
    int gid = blockIdx.x * 256 + threadIdx.x;
    const int total = N_NODES * 32;
    const int stride = 1024 * 256;  // multiple of 32 -> column fixed per thread
    float s = 0.0f;
    for (int i = gid; i < total; i += stride) s += h[i];
    s += __shfl_xor(s, 32);  // lanes l and l^32 share the same column
    __shared__ float sP[4][32];
    int wave = threadIdx.x >> 6, lane = threadIdx.x & 63;
    if (lane < 32) sP[wave][lane] = s;
    __syncthreads();
    if (threadIdx.x < 32) {
        float v = sP[0][threadIdx.x] + sP[1][threadIdx.x] + sP[2][threadIdx.x] +
                  sP[3][threadIdx.x];
        atomicAdd(&colsum[threadIdx.x], v);
    }
}

// ------------- context = tanh(colmean @ W_att) -------------
__global__ void k_context(const float* __restrict__ colsum,
                          const float* __restrict__ Watt,
                          float* __restrict__ ctx) {
    int o = threadIdx.x;  // 32 threads
    float acc = 0.0f;
#pragma unroll
    for (int f = 0; f < 32; ++f)
        acc += (colsum[f] * (1.0f / N_NODES)) * Watt[f * 32 + o];
    ctx[o] = tanhf(acc);
}

// ------------- attention pool: pooled = sum_i sigmoid(h_i . ctx) * h_i ----
__global__ __launch_bounds__(256) void k_attpool(const float* __restrict__ h,
                                                 const float* __restrict__ ctx,
                                                 float* __restrict__ pooled) {
    __shared__ float sC[32];
    __shared__ float sP[32];
    int t = threadIdx.x;
    if (t < 32) { sC[t] = ctx[t]; sP[t] = 0.0f; }
    __syncthreads();
    int n = blockIdx.x * 256 + t;
    if (n < N_NODES) {
        const float4* row = reinterpret_cast<const float4*>(h + (size_t)n * 32);
        float4 r[8];
        float dot = 0.0f;
#pragma unroll
        for (int q = 0; q < 8; ++q) {
            r[q] = row[q];
            dot += r[q].x * sC[q * 4] + r[q].y * sC[q * 4 + 1] +
                   r[q].z * sC[q * 4 + 2] + r[q].w * sC[q * 4 + 3];
        }
        float att = 1.0f / (1.0f + expf(-dot));
#pragma unroll
        for (int q = 0; q < 8; ++q) {
            atomicAdd(&sP[q * 4 + 0], att * r[q].x);
            atomicAdd(&sP[q * 4 + 1], att * r[q].y);
            atomicAdd(&sP[q * 4 + 2], att * r[q].z);
            atomicAdd(&sP[q * 4 + 3], att * r[q].w);
        }
    }
    __syncthreads();
    if (t < 32) atomicAdd(&pooled[t], sP[t]);
}

// ------------- head: relu(pooled@W_fc+b) @ W_s + b_s -> sigmoid ----------
__global__ void k_head(const float* __restrict__ pooled,
                       const float* __restrict__ Wfc, const float* __restrict__ bfc,
                       const float* __restrict__ Ws, const float* __restrict__ bs,
                       float* __restrict__ out) {
    __shared__ float sH[16];
    int t = threadIdx.x;  // 64 threads
    if (t < 16) {
        float acc = bfc[t];
#pragma unroll
        for (int f = 0; f < 32; ++f) acc += pooled[f] * Wfc[f * 16 + t];
        sH[t] = fmaxf(acc, 0.0f);
    }
    __syncthreads();
    if (t == 0) {
        float s = bs[0];
#pragma unroll
        for (int j = 0; j < 16; ++j) s += sH[j] * Ws[j];
        out[0] = 1.0f / (1.0f + expf(-s));
    }
}

extern "C" void kernel_launch(void* const* d_in, const int* in_sizes, int n_in,
                              void* d_out, int out_size, void* d_ws, size_t ws_size,
                              hipStream_t stream) {
    const float* feat = (const float*)d_in[0];
    const int* ei = (const int*)d_in[1];
    const float* W1l = (const float*)d_in[2];
    const float* b1 = (const float*)d_in[3];
    const float* W1r = (const float*)d_in[4];
    const float* W2l = (const float*)d_in[5];
    const float* b2 = (const float*)d_in[6];
    const float* W2r = (const float*)d_in[7];
    const float* W3l = (const float*)d_in[8];
    const float* b3 = (const float*)d_in[9];
    const float* W3r = (const float*)d_in[10];
    const float* Watt = (const float*)d_in[11];
    const float* Wfc = (const float*)d_in[12];
    const float* bfc = (const float*)d_in[13];
    const float* Ws = (const float*)d_in[14];
    const float* bs = (const float*)d_in[15];
    float* out = (float*)d_out;

    float* ws = (float*)d_ws;
    float* deg = ws;                       // 102400 slots (100000 used)
    float* bufA = ws + 102400;             // N*64
    float* bufB = bufA + (size_t)N_NODES * 64;  // N*64
    float* bufC = bufB + (size_t)N_NODES * 64;  // N*32
    float* colsum = bufC + (size_t)N_NODES * 32;  // 32
    float* ctx = colsum + 32;                     // 32
    float* pooled = ctx + 32;                     // 32

    // zero what accumulates
    hipMemsetAsync(deg, 0, N_NODES * sizeof(float), stream);
    hipMemsetAsync(bufA, 0, (size_t)N_NODES * 64 * sizeof(float), stream);
    hipMemsetAsync(colsum, 0, 96 * sizeof(float), stream);

    k_deg<<<N_EDGES / 256, 256, 0, stream>>>(ei + N_EDGES, deg);

    // ---- layer 1 ----
    k_scatter<64><<<N_EDGES * 16 / 256, 256, 0, stream>>>(feat, ei, bufA);
    k_sage64<true><<<N_NODES / 32, 256, 0, stream>>>(feat, bufA, deg, W1l, b1, W1r, bufB);

    // ---- layer 2 (in-place on bufB) ----
    hipMemsetAsync(bufA, 0, (size_t)N_NODES * 64 * sizeof(float), stream);
    k_scatter<64><<<N_EDGES * 16 / 256, 256, 0, stream>>>(bufB, ei, bufA);
    k_sage64<true><<<N_NODES / 32, 256, 0, stream>>>(bufB, bufA, deg, W2l, b2, W2r, bufB);

    // ---- layer 3: pre-transform, scatter 32-wide, finalize ----
    k_pretrans<<<(N_NODES + 63) / 64, 256, 0, stream>>>(bufB, W3l, bufC);
    hipMemsetAsync(bufA, 0, (size_t)N_NODES * 32 * sizeof(float), stream);
    k_scatter<32><<<N_EDGES * 8 / 256, 256, 0, stream>>>(bufC, ei, bufA);
    k_fin3<<<(N_NODES + 63) / 64, 256, 0, stream>>>(bufB, bufA, deg, b3, W3r, bufC);

    // ---- attention pooling + head ----
    k_colsum<<<1024, 256, 0, stream>>>(bufC, colsum);
    k_context<<<1, 32, 0, stream>>>(colsum, Watt, ctx);
    k_attpool<<<(N_NODES + 255) / 256, 256, 0, stream>>>(bufC, ctx, pooled);
    k_head<<<1, 64, 0, stream>>>(pooled, Wfc, bfc, Ws, bs, out);
}

// Round 2
// 844.919 us; speedup vs baseline: 4.6227x; 4.6227x over previous
//
#include <hip/hip_runtime.h>
#include <hip/hip_bf16.h>
#include <math.h>

#define N_NODES 100000
#define N_EDGES 1600000
#define SCAN_BLOCKS 98  // ceil(100000/1024)

// ---------------- histogram of targets (int) ----------------
__global__ __launch_bounds__(256) void k_count(const int* __restrict__ tgt,
                                               int* __restrict__ counts) {
    int e = blockIdx.x * 256 + threadIdx.x;
    if (e < N_EDGES) atomicAdd(&counts[tgt[e]], 1);
}

// ---------------- block-local exclusive scan (1024/block) ----------------
__global__ __launch_bounds__(256) void k_scanA(const int* __restrict__ counts,
                                               int* __restrict__ rowptr,
                                               int* __restrict__ bsum) {
    int t = threadIdx.x;
    int base = blockIdx.x * 1024 + t * 4;
    int v0 = (base + 0 < N_NODES) ? counts[base + 0] : 0;
    int v1 = (base + 1 < N_NODES) ? counts[base + 1] : 0;
    int v2 = (base + 2 < N_NODES) ? counts[base + 2] : 0;
    int v3 = (base + 3 < N_NODES) ? counts[base + 3] : 0;
    int s = v0 + v1 + v2 + v3;
    __shared__ int sS[256];
    sS[t] = s;
    __syncthreads();
    for (int off = 1; off < 256; off <<= 1) {
        int add = (t >= off) ? sS[t - off] : 0;
        __syncthreads();
        sS[t] += add;
        __syncthreads();
    }
    int excl = sS[t] - s;
    if (t == 255) bsum[blockIdx.x] = sS[255];
    if (base + 0 < N_NODES) rowptr[base + 0] = excl;
    if (base + 1 < N_NODES) rowptr[base + 1] = excl + v0;
    if (base + 2 < N_NODES) rowptr[base + 2] = excl + v0 + v1;
    if (base + 3 < N_NODES) rowptr[base + 3] = excl + v0 + v1 + v2;
}

__global__ void k_scanB(const int* __restrict__ bsum, int* __restrict__ boff) {
    __shared__ int sD[128];
    int t = threadIdx.x;  // 128 threads
    int v = (t < SCAN_BLOCKS) ? bsum[t] : 0;
    sD[t] = v;
    __syncthreads();
    for (int off = 1; off < 128; off <<= 1) {
        int add = (t >= off) ? sD[t - off] : 0;
        __syncthreads();
        sD[t] += add;
        __syncthreads();
    }
    boff[t] = sD[t] - v;
}

__global__ __launch_bounds__(256) void k_scanC(int* __restrict__ rowptr,
                                               const int* __restrict__ boff) {
    int t = threadIdx.x;
    int base = blockIdx.x * 1024 + t * 4;
    int add = boff[blockIdx.x];
    if (base + 0 < N_NODES) rowptr[base + 0] += add;
    if (base + 1 < N_NODES) rowptr[base + 1] += add;
    if (base + 2 < N_NODES) rowptr[base + 2] += add;
    if (base + 3 < N_NODES) rowptr[base + 3] += add;
    if (blockIdx.x == 0 && t == 0) rowptr[N_NODES] = N_EDGES;
}

// ---------------- CSR fill ----------------
__global__ __launch_bounds__(256) void k_fill(const int* __restrict__ ei,
                                              const int* __restrict__ rowptr,
                                              int* __restrict__ cursor,
                                              int* __restrict__ csr) {
    int e = blockIdx.x * 256 + threadIdx.x;
    if (e < N_EDGES) {
        int s = ei[e];
        int t = ei[N_EDGES + e];
        int pos = rowptr[t] + atomicAdd(&cursor[t], 1);
        csr[pos] = s;
    }
}

// ---------------- gather-mean, D=64: one wave per node ----------------
__global__ __launch_bounds__(256) void k_gather64(const float* __restrict__ x,
                                                  const int* __restrict__ rowptr,
                                                  const int* __restrict__ csr,
                                                  float* __restrict__ agg) {
    int wid = (blockIdx.x * 256 + threadIdx.x) >> 6;  // node
    int lane = threadIdx.x & 63;
    if (wid >= N_NODES) return;
    int rs = rowptr[wid], re = rowptr[wid + 1];
    float a0 = 0.f, a1 = 0.f, a2 = 0.f, a3 = 0.f;
    for (int base = rs; base < re; base += 64) {
        int j = base + lane;
        int idx = (j < re) ? csr[j] : 0;
        int cnt = min(64, re - base);
        int k = 0;
        for (; k + 4 <= cnt; k += 4) {
            int s0 = __shfl(idx, k + 0);
            int s1 = __shfl(idx, k + 1);
            int s2 = __shfl(idx, k + 2);
            int s3 = __shfl(idx, k + 3);
            a0 += x[(size_t)s0 * 64 + lane];
            a1 += x[(size_t)s1 * 64 + lane];
            a2 += x[(size_t)s2 * 64 + lane];
            a3 += x[(size_t)s3 * 64 + lane];
        }
        for (; k < cnt; ++k) {
            int s = __shfl(idx, k);
            a0 += x[(size_t)s * 64 + lane];
        }
    }
    float acc = (a0 + a1) + (a2 + a3);
    float invd = 1.0f / fmaxf((float)(re - rs), 1.0f);
    agg[(size_t)wid * 64 + lane] = acc * invd;
}

// ---------------- gather-mean, D=32: one wave per node, 2 edge-halves ------
__global__ __launch_bounds__(256) void k_gather32(const float* __restrict__ z,
                                                  const int* __restrict__ rowptr,
                                                  const int* __restrict__ csr,
                                                  float* __restrict__ agg) {
    int wid = (blockIdx.x * 256 + threadIdx.x) >> 6;  // node
    int lane = threadIdx.x & 63;
    int h = lane >> 5, o = lane & 31;
    if (wid >= N_NODES) return;
    int rs = rowptr[wid], re = rowptr[wid + 1];
    float a0 = 0.f, a1 = 0.f;
    for (int base = rs; base < re; base += 64) {
        int j = base + lane;
        int idx = (j < re) ? csr[j] : 0;
        int cnt = re - base;
        int k0 = h * 32;
        int k1 = min(cnt, k0 + 32);
        int k = k0;
        for (; k + 2 <= k1; k += 2) {
            int s0 = __shfl(idx, k + 0);
            int s1 = __shfl(idx, k + 1);
            a0 += z[(size_t)s0 * 32 + o];
            a1 += z[(size_t)s1 * 32 + o];
        }
        for (; k < k1; ++k) {
            int s = __shfl(idx, k);
            a0 += z[(size_t)s * 32 + o];
        }
    }
    float acc = a0 + a1;
    acc += __shfl_xor(acc, 32);
    if (h == 0) {
        float invd = 1.0f / fmaxf((float)(re - rs), 1.0f);
        agg[(size_t)wid * 32 + o] = acc * invd;
    }
}

// ------------- SAGE transform 64->64 (agg pre-averaged) -------------
template <bool RELU>
__global__ __launch_bounds__(256) void k_xform64(const float* __restrict__ x,
                                                 const float* __restrict__ agg,
                                                 const float* __restrict__ Wl,
                                                 const float* __restrict__ b,
                                                 const float* __restrict__ Wr,
                                                 float* __restrict__ out) {
    __shared__ float sWl[4096], sWr[4096];
    __shared__ float sA[4][64], sX[4][64];
    int t = threadIdx.x;
    for (int i = t; i < 4096; i += 256) { sWl[i] = Wl[i]; sWr[i] = Wr[i]; }
    int ln = t >> 6, o = t & 63;
    for (int it = 0; it < 8; ++it) {
        int node = blockIdx.x * 32 + it * 4 + ln;
        __syncthreads();
        sA[ln][o] = agg[(size_t)node * 64 + o];
        sX[ln][o] = x[(size_t)node * 64 + o];
        __syncthreads();
        float acc = b[o];
#pragma unroll
        for (int f = 0; f < 64; ++f)
            acc += sA[ln][f] * sWl[f * 64 + o] + sX[ln][f] * sWr[f * 64 + o];
        float ss = acc * acc;
#pragma unroll
        for (int m = 32; m; m >>= 1) ss += __shfl_xor(ss, m);
        float v = acc / fmaxf(sqrtf(ss), 1e-12f);
        if (RELU) v = fmaxf(v, 0.0f);
        out[(size_t)node * 64 + o] = v;
    }
}

// ------------- pre-transform layer3: z = x @ W3l  (64 -> 32) -------------
__global__ __launch_bounds__(256) void k_pretrans(const float* __restrict__ x,
                                                  const float* __restrict__ W,
                                                  float* __restrict__ z) {
    __shared__ float sW[2048];
    __shared__ float sX[8][64];
    int t = threadIdx.x;
    for (int i = t; i < 2048; i += 256) sW[i] = W[i];
    int ln = t >> 5, o = t & 31;
    for (int it = 0; it < 8; ++it) {
        int node = blockIdx.x * 64 + it * 8 + ln;
        __syncthreads();
        if (node < N_NODES) {
            sX[ln][o] = x[(size_t)node * 64 + o];
            sX[ln][o + 32] = x[(size_t)node * 64 + o + 32];
        }
        __syncthreads();
        if (node < N_NODES) {
            float acc = 0.0f;
#pragma unroll
            for (int f = 0; f < 64; ++f) acc += sX[ln][f] * sW[f * 32 + o];
            z[(size_t)node * 32 + o] = acc;
        }
    }
}

// ------------- layer3 finalize (agg32 pre-averaged) -------------
__global__ __launch_bounds__(256) void k_fin3(const float* __restrict__ x,
                                              const float* __restrict__ agg32,
                                              const float* __restrict__ b,
                                              const float* __restrict__ Wr,
                                              float* __restrict__ out) {
    __shared__ float sW[2048];
    __shared__ float sX[8][64];
    int t = threadIdx.x;
    for (int i = t; i < 2048; i += 256) sW[i] = Wr[i];
    int ln = t >> 5, o = t & 31;
    for (int it = 0; it < 8; ++it) {
        int node = blockIdx.x * 64 + it * 8 + ln;
        __syncthreads();
        if (node < N_NODES) {
            sX[ln][o] = x[(size_t)node * 64 + o];
            sX[ln][o + 32] = x[(size_t)node * 64 + o + 32];
        }
        __syncthreads();
        if (node < N_NODES) {
            float acc = agg32[(size_t)node * 32 + o] + b[o];
#pragma unroll
            for (int f = 0; f < 64; ++f) acc += sX[ln][f] * sW[f * 32 + o];
            float ss = acc * acc;
#pragma unroll
            for (int m = 16; m; m >>= 1) ss += __shfl_xor(ss, m);
            out[(size_t)node * 32 + o] = acc / fmaxf(sqrtf(ss), 1e-12f);
        }
    }
}

// ------------- column sum of h3 [N,32] -------------
__global__ __launch_bounds__(256) void k_colsum(const float* __restrict__ h,
                                                float* __restrict__ colsum) {
    int gid = blockIdx.x * 256 + threadIdx.x;
    const int total = N_NODES * 32;
    const int stride = 1024 * 256;
    float s = 0.0f;
    for (int i = gid; i < total; i += stride) s += h[i];
    s += __shfl_xor(s, 32);
    __shared__ float sP[4][32];
    int wave = threadIdx.x >> 6, lane = threadIdx.x & 63;
    if (lane < 32) sP[wave][lane] = s;
    __syncthreads();
    if (threadIdx.x < 32) {
        float v = sP[0][threadIdx.x] + sP[1][threadIdx.x] + sP[2][threadIdx.x] +
                  sP[3][threadIdx.x];
        atomicAdd(&colsum[threadIdx.x], v);
    }
}

__global__ void k_context(const float* __restrict__ colsum,
                          const float* __restrict__ Watt,
                          float* __restrict__ ctx) {
    int o = threadIdx.x;  // 32 threads
    float acc = 0.0f;
#pragma unroll
    for (int f = 0; f < 32; ++f)
        acc += (colsum[f] * (1.0f / N_NODES)) * Watt[f * 32 + o];
    ctx[o] = tanhf(acc);
}

__global__ __launch_bounds__(256) void k_attpool(const float* __restrict__ h,
                                                 const float* __restrict__ ctx,
                                                 float* __restrict__ pooled) {
    __shared__ float sC[32];
    __shared__ float sP[32];
    int t = threadIdx.x;
    if (t < 32) { sC[t] = ctx[t]; sP[t] = 0.0f; }
    __syncthreads();
    int n = blockIdx.x * 256 + t;
    if (n < N_NODES) {
        const float4* row = reinterpret_cast<const float4*>(h + (size_t)n * 32);
        float4 r[8];
        float dot = 0.0f;
#pragma unroll
        for (int q = 0; q < 8; ++q) {
            r[q] = row[q];
            dot += r[q].x * sC[q * 4] + r[q].y * sC[q * 4 + 1] +
                   r[q].z * sC[q * 4 + 2] + r[q].w * sC[q * 4 + 3];
        }
        float att = 1.0f / (1.0f + expf(-dot));
#pragma unroll
        for (int q = 0; q < 8; ++q) {
            atomicAdd(&sP[q * 4 + 0], att * r[q].x);
            atomicAdd(&sP[q * 4 + 1], att * r[q].y);
            atomicAdd(&sP[q * 4 + 2], att * r[q].z);
            atomicAdd(&sP[q * 4 + 3], att * r[q].w);
        }
    }
    __syncthreads();
    if (t < 32) atomicAdd(&pooled[t], sP[t]);
}

__global__ void k_head(const float* __restrict__ pooled,
                       const float* __restrict__ Wfc, const float* __restrict__ bfc,
                       const float* __restrict__ Ws, const float* __restrict__ bs,
                       float* __restrict__ out) {
    __shared__ float sH[16];
    int t = threadIdx.x;  // 64 threads
    if (t < 16) {
        float acc = bfc[t];
#pragma unroll
        for (int f = 0; f < 32; ++f) acc += pooled[f] * Wfc[f * 16 + t];
        sH[t] = fmaxf(acc, 0.0f);
    }
    __syncthreads();
    if (t == 0) {
        float s = bs[0];
#pragma unroll
        for (int j = 0; j < 16; ++j) s += sH[j] * Ws[j];
        out[0] = 1.0f / (1.0f + expf(-s));
    }
}

extern "C" void kernel_launch(void* const* d_in, const int* in_sizes, int n_in,
                              void* d_out, int out_size, void* d_ws, size_t ws_size,
                              hipStream_t stream) {
    const float* feat = (const float*)d_in[0];
    const int* ei = (const int*)d_in[1];
    const float* W1l = (const float*)d_in[2];
    const float* b1 = (const float*)d_in[3];
    const float* W1r = (const float*)d_in[4];
    const float* W2l = (const float*)d_in[5];
    const float* b2 = (const float*)d_in[6];
    const float* W2r = (const float*)d_in[7];
    const float* W3l = (const float*)d_in[8];
    const float* b3 = (const float*)d_in[9];
    const float* W3r = (const float*)d_in[10];
    const float* Watt = (const float*)d_in[11];
    const float* Wfc = (const float*)d_in[12];
    const float* bfc = (const float*)d_in[13];
    const float* Ws = (const float*)d_in[14];
    const float* bs = (const float*)d_in[15];
    float* out = (float*)d_out;

    // ---- workspace layout (4-byte units) ----
    int* rowptr = (int*)d_ws;                 // 100001
    int* cursor = rowptr + 100002;            // 100000 (doubles as counts)
    int* bsum = cursor + 100000;              // 128
    int* boff = bsum + 128;                   // 128
    int* csr = boff + 128;                    // 1,600,000
    float* bufA = (float*)(csr + N_EDGES);    // N*64
    float* bufB = bufA + (size_t)N_NODES * 64;  // N*64
    float* colsum = bufB + (size_t)N_NODES * 64;  // 32
    float* ctx = colsum + 32;
    float* pooled = ctx + 32;
    // total ~58.5 MB

    // ---- CSR build ----
    hipMemsetAsync(cursor, 0, N_NODES * sizeof(int), stream);       // counts
    hipMemsetAsync(colsum, 0, 96 * sizeof(float), stream);
    k_count<<<N_EDGES / 256, 256, 0, stream>>>(ei + N_EDGES, cursor);
    k_scanA<<<SCAN_BLOCKS, 256, 0, stream>>>(cursor, rowptr, bsum);
    k_scanB<<<1, 128, 0, stream>>>(bsum, boff);
    k_scanC<<<SCAN_BLOCKS, 256, 0, stream>>>(rowptr, boff);
    hipMemsetAsync(cursor, 0, N_NODES * sizeof(int), stream);       // cursors
    k_fill<<<N_EDGES / 256, 256, 0, stream>>>(ei, rowptr, cursor, csr);

    // ---- layer 1: gather feat -> bufA; xform -> h1 = bufB ----
    k_gather64<<<25000, 256, 0, stream>>>(feat, rowptr, csr, bufA);
    k_xform64<true><<<N_NODES / 32, 256, 0, stream>>>(feat, bufA, W1l, b1, W1r, bufB);

    // ---- layer 2: gather h1 -> bufA; xform (in-place) -> h2 = bufA ----
    k_gather64<<<25000, 256, 0, stream>>>(bufB, rowptr, csr, bufA);
    k_xform64<true><<<N_NODES / 32, 256, 0, stream>>>(bufB, bufA, W2l, b2, W2r, bufA);

    // ---- layer 3: pretrans h2 -> z = bufB[0:N*32]; gather32 -> bufB[N*32:];
    //      finalize -> h3 = bufB[0:N*32] ----
    float* z = bufB;
    float* agg32 = bufB + (size_t)N_NODES * 32;
    k_pretrans<<<(N_NODES + 63) / 64, 256, 0, stream>>>(bufA, W3l, z);
    k_gather32<<<25000, 256, 0, stream>>>(z, rowptr, csr, agg32);
    k_fin3<<<(N_NODES + 63) / 64, 256, 0, stream>>>(bufA, agg32, b3, W3r, z);

    // ---- attention pooling + head (h3 = bufB[0:N*32]) ----
    k_colsum<<<1024, 256, 0, stream>>>(bufB, colsum);
    k_context<<<1, 32, 0, stream>>>(colsum, Watt, ctx);
    k_attpool<<<(N_NODES + 255) / 256, 256, 0, stream>>>(bufB, ctx, pooled);
    k_head<<<1, 64, 0, stream>>>(pooled, Wfc, bfc, Ws, bs, out);
}

// Round 3
// 777.691 us; speedup vs baseline: 5.0224x; 1.0864x over previous
//
#include <hip/hip_runtime.h>
#include <hip/hip_bf16.h>
#include <math.h>

#define N_NODES 100000
#define N_EDGES 1600000
#define SCAN_BLOCKS 98  // ceil(100000/1024)

__device__ __forceinline__ float bcast(float v, int l) {
    return __int_as_float(__builtin_amdgcn_readlane(__float_as_int(v), l));
}

// ---------------- histogram of targets (int) ----------------
__global__ __launch_bounds__(256) void k_count(const int* __restrict__ tgt,
                                               int* __restrict__ counts) {
    int e = blockIdx.x * 256 + threadIdx.x;
    if (e < N_EDGES) atomicAdd(&counts[tgt[e]], 1);
}

// ---------------- block-local exclusive scan (1024/block) ----------------
__global__ __launch_bounds__(256) void k_scanA(const int* __restrict__ counts,
                                               int* __restrict__ rowptr,
                                               int* __restrict__ bsum) {
    int t = threadIdx.x;
    int base = blockIdx.x * 1024 + t * 4;
    int v0 = (base + 0 < N_NODES) ? counts[base + 0] : 0;
    int v1 = (base + 1 < N_NODES) ? counts[base + 1] : 0;
    int v2 = (base + 2 < N_NODES) ? counts[base + 2] : 0;
    int v3 = (base + 3 < N_NODES) ? counts[base + 3] : 0;
    int s = v0 + v1 + v2 + v3;
    __shared__ int sS[256];
    sS[t] = s;
    __syncthreads();
    for (int off = 1; off < 256; off <<= 1) {
        int add = (t >= off) ? sS[t - off] : 0;
        __syncthreads();
        sS[t] += add;
        __syncthreads();
    }
    int excl = sS[t] - s;
    if (t == 255) bsum[blockIdx.x] = sS[255];
    if (base + 0 < N_NODES) rowptr[base + 0] = excl;
    if (base + 1 < N_NODES) rowptr[base + 1] = excl + v0;
    if (base + 2 < N_NODES) rowptr[base + 2] = excl + v0 + v1;
    if (base + 3 < N_NODES) rowptr[base + 3] = excl + v0 + v1 + v2;
}

__global__ void k_scanB(const int* __restrict__ bsum, int* __restrict__ boff) {
    __shared__ int sD[128];
    int t = threadIdx.x;  // 128 threads
    int v = (t < SCAN_BLOCKS) ? bsum[t] : 0;
    sD[t] = v;
    __syncthreads();
    for (int off = 1; off < 128; off <<= 1) {
        int add = (t >= off) ? sD[t - off] : 0;
        __syncthreads();
        sD[t] += add;
        __syncthreads();
    }
    boff[t] = sD[t] - v;
}

__global__ __launch_bounds__(256) void k_scanC(int* __restrict__ rowptr,
                                               const int* __restrict__ boff) {
    int t = threadIdx.x;
    int base = blockIdx.x * 1024 + t * 4;
    int add = boff[blockIdx.x];
    if (base + 0 < N_NODES) rowptr[base + 0] += add;
    if (base + 1 < N_NODES) rowptr[base + 1] += add;
    if (base + 2 < N_NODES) rowptr[base + 2] += add;
    if (base + 3 < N_NODES) rowptr[base + 3] += add;
    if (blockIdx.x == 0 && t == 0) rowptr[N_NODES] = N_EDGES;
}

// ---------------- CSR fill ----------------
__global__ __launch_bounds__(256) void k_fill(const int* __restrict__ ei,
                                              const int* __restrict__ rowptr,
                                              int* __restrict__ cursor,
                                              int* __restrict__ csr) {
    int e = blockIdx.x * 256 + threadIdx.x;
    if (e < N_EDGES) {
        int s = ei[e];
        int t = ei[N_EDGES + e];
        int pos = rowptr[t] + atomicAdd(&cursor[t], 1);
        csr[pos] = s;
    }
}

// ---------------- gather-mean, D=64: one wave per node ----------------
__global__ __launch_bounds__(256) void k_gather64(const float* __restrict__ x,
                                                  const int* __restrict__ rowptr,
                                                  const int* __restrict__ csr,
                                                  float* __restrict__ agg) {
    int wid = (blockIdx.x * 256 + threadIdx.x) >> 6;  // node
    int lane = threadIdx.x & 63;
    if (wid >= N_NODES) return;
    int rs = rowptr[wid], re = rowptr[wid + 1];
    float a0 = 0.f, a1 = 0.f, a2 = 0.f, a3 = 0.f;
    for (int base = rs; base < re; base += 64) {
        int j = base + lane;
        int idx = (j < re) ? csr[j] : 0;
        int cnt = min(64, re - base);
        int k = 0;
        for (; k + 4 <= cnt; k += 4) {
            int s0 = __shfl(idx, k + 0);
            int s1 = __shfl(idx, k + 1);
            int s2 = __shfl(idx, k + 2);
            int s3 = __shfl(idx, k + 3);
            a0 += x[(size_t)s0 * 64 + lane];
            a1 += x[(size_t)s1 * 64 + lane];
            a2 += x[(size_t)s2 * 64 + lane];
            a3 += x[(size_t)s3 * 64 + lane];
        }
        for (; k < cnt; ++k) {
            int s = __shfl(idx, k);
            a0 += x[(size_t)s * 64 + lane];
        }
    }
    float acc = (a0 + a1) + (a2 + a3);
    float invd = 1.0f / fmaxf((float)(re - rs), 1.0f);
    agg[(size_t)wid * 64 + lane] = acc * invd;
}

// ---------------- gather-mean, D=32: one wave per node, 2 edge-halves ------
__global__ __launch_bounds__(256) void k_gather32(const float* __restrict__ z,
                                                  const int* __restrict__ rowptr,
                                                  const int* __restrict__ csr,
                                                  float* __restrict__ agg) {
    int wid = (blockIdx.x * 256 + threadIdx.x) >> 6;  // node
    int lane = threadIdx.x & 63;
    int h = lane >> 5, o = lane & 31;
    if (wid >= N_NODES) return;
    int rs = rowptr[wid], re = rowptr[wid + 1];
    float a0 = 0.f, a1 = 0.f;
    for (int base = rs; base < re; base += 64) {
        int j = base + lane;
        int idx = (j < re) ? csr[j] : 0;
        int cnt = re - base;
        int k0 = h * 32;
        int k1 = min(cnt, k0 + 32);
        int k = k0;
        for (; k + 2 <= k1; k += 2) {
            int s0 = __shfl(idx, k + 0);
            int s1 = __shfl(idx, k + 1);
            a0 += z[(size_t)s0 * 32 + o];
            a1 += z[(size_t)s1 * 32 + o];
        }
        for (; k < k1; ++k) {
            int s = __shfl(idx, k);
            a0 += z[(size_t)s * 32 + o];
        }
    }
    float acc = a0 + a1;
    acc += __shfl_xor(acc, 32);
    if (h == 0) {
        float invd = 1.0f / fmaxf((float)(re - rs), 1.0f);
        agg[(size_t)wid * 32 + o] = acc * invd;
    }
}

// ------------- SAGE transform 64->64, register weights + readlane ----------
// One node per wave; weight columns in VGPRs; broadcasts via v_readlane.
template <bool RELU>
__global__ __launch_bounds__(256) void k_xform64(const float* __restrict__ x,
                                                 const float* __restrict__ agg,
                                                 const float* __restrict__ Wl,
                                                 const float* __restrict__ b,
                                                 const float* __restrict__ Wr,
                                                 float* __restrict__ out) {
    int lane = threadIdx.x & 63;
    int wv = (blockIdx.x * 256 + threadIdx.x) >> 6;
    int nw = gridDim.x * 4;
    float wl[64], wr[64];
#pragma unroll
    for (int f = 0; f < 64; ++f) {
        wl[f] = Wl[f * 64 + lane];
        wr[f] = Wr[f * 64 + lane];
    }
    float breg = b[lane];
    for (int node = wv; node < N_NODES; node += nw) {
        float a = agg[(size_t)node * 64 + lane];
        float xr = x[(size_t)node * 64 + lane];
        float acc0 = breg, acc1 = 0.f;
#pragma unroll
        for (int f = 0; f < 64; ++f) {
            acc0 = fmaf(bcast(a, f), wl[f], acc0);
            acc1 = fmaf(bcast(xr, f), wr[f], acc1);
        }
        float v = acc0 + acc1;
        float ss = v * v;
#pragma unroll
        for (int m = 32; m; m >>= 1) ss += __shfl_xor(ss, m);
        float o = v / fmaxf(sqrtf(ss), 1e-12f);
        if (RELU) o = fmaxf(o, 0.0f);
        out[(size_t)node * 64 + lane] = o;
    }
}

// ------------- pre-transform layer3: z = x @ W3l (64 -> 32) -------------
// One node per wave; lanes >=32 mirror lanes <32 (redundant but branch-free).
__global__ __launch_bounds__(256) void k_pretrans(const float* __restrict__ x,
                                                  const float* __restrict__ W,
                                                  float* __restrict__ z) {
    int lane = threadIdx.x & 63;
    int o = lane & 31;
    int wv = (blockIdx.x * 256 + threadIdx.x) >> 6;
    int nw = gridDim.x * 4;
    float wc[64];
#pragma unroll
    for (int f = 0; f < 64; ++f) wc[f] = W[f * 32 + o];
    for (int node = wv; node < N_NODES; node += nw) {
        float xr = x[(size_t)node * 64 + lane];
        float acc = 0.f;
#pragma unroll
        for (int f = 0; f < 64; ++f) acc = fmaf(bcast(xr, f), wc[f], acc);
        if (lane < 32) z[(size_t)node * 32 + o] = acc;
    }
}

// ------------- layer3 finalize: out = normalize(agg32 + b + x @ W3r) -------
__global__ __launch_bounds__(256) void k_fin3(const float* __restrict__ x,
                                              const float* __restrict__ agg32,
                                              const float* __restrict__ b,
                                              const float* __restrict__ Wr,
                                              float* __restrict__ out) {
    int lane = threadIdx.x & 63;
    int o = lane & 31;
    int wv = (blockIdx.x * 256 + threadIdx.x) >> 6;
    int nw = gridDim.x * 4;
    float wc[64];
#pragma unroll
    for (int f = 0; f < 64; ++f) wc[f] = Wr[f * 32 + o];
    float breg = b[o];
    for (int node = wv; node < N_NODES; node += nw) {
        float xr = x[(size_t)node * 64 + lane];
        float acc = agg32[(size_t)node * 32 + o] + breg;
#pragma unroll
        for (int f = 0; f < 64; ++f) acc = fmaf(bcast(xr, f), wc[f], acc);
        // lanes l and l+32 hold identical acc; reduce within each 32-group
        float ss = acc * acc;
#pragma unroll
        for (int m = 16; m; m >>= 1) ss += __shfl_xor(ss, m);
        if (lane < 32) out[(size_t)node * 32 + o] = acc / fmaxf(sqrtf(ss), 1e-12f);
    }
}

// ------------- column sum of h3 [N,32] -------------
__global__ __launch_bounds__(256) void k_colsum(const float* __restrict__ h,
                                                float* __restrict__ colsum) {
    int gid = blockIdx.x * 256 + threadIdx.x;
    const int total = N_NODES * 32;
    const int stride = 1024 * 256;
    float s = 0.0f;
    for (int i = gid; i < total; i += stride) s += h[i];
    s += __shfl_xor(s, 32);
    __shared__ float sP[4][32];
    int wave = threadIdx.x >> 6, lane = threadIdx.x & 63;
    if (lane < 32) sP[wave][lane] = s;
    __syncthreads();
    if (threadIdx.x < 32) {
        float v = sP[0][threadIdx.x] + sP[1][threadIdx.x] + sP[2][threadIdx.x] +
                  sP[3][threadIdx.x];
        atomicAdd(&colsum[threadIdx.x], v);
    }
}

__global__ void k_context(const float* __restrict__ colsum,
                          const float* __restrict__ Watt,
                          float* __restrict__ ctx) {
    int o = threadIdx.x;  // 32 threads
    float acc = 0.0f;
#pragma unroll
    for (int f = 0; f < 32; ++f)
        acc += (colsum[f] * (1.0f / N_NODES)) * Watt[f * 32 + o];
    ctx[o] = tanhf(acc);
}

__global__ __launch_bounds__(256) void k_attpool(const float* __restrict__ h,
                                                 const float* __restrict__ ctx,
                                                 float* __restrict__ pooled) {
    __shared__ float sC[32];
    __shared__ float sP[32];
    int t = threadIdx.x;
    if (t < 32) { sC[t] = ctx[t]; sP[t] = 0.0f; }
    __syncthreads();
    int n = blockIdx.x * 256 + t;
    if (n < N_NODES) {
        const float4* row = reinterpret_cast<const float4*>(h + (size_t)n * 32);
        float4 r[8];
        float dot = 0.0f;
#pragma unroll
        for (int q = 0; q < 8; ++q) {
            r[q] = row[q];
            dot += r[q].x * sC[q * 4] + r[q].y * sC[q * 4 + 1] +
                   r[q].z * sC[q * 4 + 2] + r[q].w * sC[q * 4 + 3];
        }
        float att = 1.0f / (1.0f + expf(-dot));
#pragma unroll
        for (int q = 0; q < 8; ++q) {
            atomicAdd(&sP[q * 4 + 0], att * r[q].x);
            atomicAdd(&sP[q * 4 + 1], att * r[q].y);
            atomicAdd(&sP[q * 4 + 2], att * r[q].z);
            atomicAdd(&sP[q * 4 + 3], att * r[q].w);
        }
    }
    __syncthreads();
    if (t < 32) atomicAdd(&pooled[t], sP[t]);
}

__global__ void k_head(const float* __restrict__ pooled,
                       const float* __restrict__ Wfc, const float* __restrict__ bfc,
                       const float* __restrict__ Ws, const float* __restrict__ bs,
                       float* __restrict__ out) {
    __shared__ float sH[16];
    int t = threadIdx.x;  // 64 threads
    if (t < 16) {
        float acc = bfc[t];
#pragma unroll
        for (int f = 0; f < 32; ++f) acc += pooled[f] * Wfc[f * 16 + t];
        sH[t] = fmaxf(acc, 0.0f);
    }
    __syncthreads();
    if (t == 0) {
        float s = bs[0];
#pragma unroll
        for (int j = 0; j < 16; ++j) s += sH[j] * Ws[j];
        out[0] = 1.0f / (1.0f + expf(-s));
    }
}

extern "C" void kernel_launch(void* const* d_in, const int* in_sizes, int n_in,
                              void* d_out, int out_size, void* d_ws, size_t ws_size,
                              hipStream_t stream) {
    const float* feat = (const float*)d_in[0];
    const int* ei = (const int*)d_in[1];
    const float* W1l = (const float*)d_in[2];
    const float* b1 = (const float*)d_in[3];
    const float* W1r = (const float*)d_in[4];
    const float* W2l = (const float*)d_in[5];
    const float* b2 = (const float*)d_in[6];
    const float* W2r = (const float*)d_in[7];
    const float* W3l = (const float*)d_in[8];
    const float* b3 = (const float*)d_in[9];
    const float* W3r = (const float*)d_in[10];
    const float* Watt = (const float*)d_in[11];
    const float* Wfc = (const float*)d_in[12];
    const float* bfc = (const float*)d_in[13];
    const float* Ws = (const float*)d_in[14];
    const float* bs = (const float*)d_in[15];
    float* out = (float*)d_out;

    // ---- workspace layout (4-byte units) ----
    int* rowptr = (int*)d_ws;                 // 100001
    int* cursor = rowptr + 100002;            // 100000 (doubles as counts)
    int* bsum = cursor + 100000;              // 128
    int* boff = bsum + 128;                   // 128
    int* csr = boff + 128;                    // 1,600,000
    float* bufA = (float*)(csr + N_EDGES);    // N*64
    float* bufB = bufA + (size_t)N_NODES * 64;  // N*64
    float* colsum = bufB + (size_t)N_NODES * 64;  // 32
    float* ctx = colsum + 32;
    float* pooled = ctx + 32;

    // ---- CSR build ----
    hipMemsetAsync(cursor, 0, N_NODES * sizeof(int), stream);       // counts
    hipMemsetAsync(colsum, 0, 96 * sizeof(float), stream);
    k_count<<<N_EDGES / 256, 256, 0, stream>>>(ei + N_EDGES, cursor);
    k_scanA<<<SCAN_BLOCKS, 256, 0, stream>>>(cursor, rowptr, bsum);
    k_scanB<<<1, 128, 0, stream>>>(bsum, boff);
    k_scanC<<<SCAN_BLOCKS, 256, 0, stream>>>(rowptr, boff);
    hipMemsetAsync(cursor, 0, N_NODES * sizeof(int), stream);       // cursors
    k_fill<<<N_EDGES / 256, 256, 0, stream>>>(ei, rowptr, cursor, csr);

    // ---- layer 1: gather feat -> bufA; xform -> h1 = bufB ----
    k_gather64<<<25000, 256, 0, stream>>>(feat, rowptr, csr, bufA);
    k_xform64<true><<<1024, 256, 0, stream>>>(feat, bufA, W1l, b1, W1r, bufB);

    // ---- layer 2: gather h1 -> bufA; xform (in-place) -> h2 = bufA ----
    k_gather64<<<25000, 256, 0, stream>>>(bufB, rowptr, csr, bufA);
    k_xform64<true><<<1024, 256, 0, stream>>>(bufB, bufA, W2l, b2, W2r, bufA);

    // ---- layer 3: pretrans h2 -> z; gather32 -> agg32; finalize -> h3 ----
    float* z = bufB;
    float* agg32 = bufB + (size_t)N_NODES * 32;
    k_pretrans<<<1024, 256, 0, stream>>>(bufA, W3l, z);
    k_gather32<<<25000, 256, 0, stream>>>(z, rowptr, csr, agg32);
    k_fin3<<<1024, 256, 0, stream>>>(bufA, agg32, b3, W3r, z);

    // ---- attention pooling + head (h3 = bufB[0:N*32]) ----
    k_colsum<<<1024, 256, 0, stream>>>(bufB, colsum);
    k_context<<<1, 32, 0, stream>>>(colsum, Watt, ctx);
    k_attpool<<<(N_NODES + 255) / 256, 256, 0, stream>>>(bufB, ctx, pooled);
    k_head<<<1, 64, 0, stream>>>(pooled, Wfc, bfc, Ws, bs, out);
}

// Round 4
// 767.995 us; speedup vs baseline: 5.0858x; 1.0126x over previous
//
#include <hip/hip_runtime.h>
#include <hip/hip_bf16.h>
#include <math.h>

#define N_NODES 100000
#define N_EDGES 1600000
#define SCAN_BLOCKS 98  // ceil(100000/1024)

__device__ __forceinline__ float bcast(float v, int l) {
    return __int_as_float(__builtin_amdgcn_readlane(__float_as_int(v), l));
}

// ---------------- histogram of targets (int) ----------------
__global__ __launch_bounds__(256) void k_count(const int* __restrict__ tgt,
                                               int* __restrict__ counts) {
    int e = blockIdx.x * 256 + threadIdx.x;
    if (e < N_EDGES) atomicAdd(&counts[tgt[e]], 1);
}

// ---------------- block-local exclusive scan (1024/block) ----------------
__global__ __launch_bounds__(256) void k_scanA(const int* __restrict__ counts,
                                               int* __restrict__ rowptr,
                                               int* __restrict__ bsum) {
    int t = threadIdx.x;
    int base = blockIdx.x * 1024 + t * 4;
    int v0 = (base + 0 < N_NODES) ? counts[base + 0] : 0;
    int v1 = (base + 1 < N_NODES) ? counts[base + 1] : 0;
    int v2 = (base + 2 < N_NODES) ? counts[base + 2] : 0;
    int v3 = (base + 3 < N_NODES) ? counts[base + 3] : 0;
    int s = v0 + v1 + v2 + v3;
    __shared__ int sS[256];
    sS[t] = s;
    __syncthreads();
    for (int off = 1; off < 256; off <<= 1) {
        int add = (t >= off) ? sS[t - off] : 0;
        __syncthreads();
        sS[t] += add;
        __syncthreads();
    }
    int excl = sS[t] - s;
    if (t == 255) bsum[blockIdx.x] = sS[255];
    if (base + 0 < N_NODES) rowptr[base + 0] = excl;
    if (base + 1 < N_NODES) rowptr[base + 1] = excl + v0;
    if (base + 2 < N_NODES) rowptr[base + 2] = excl + v0 + v1;
    if (base + 3 < N_NODES) rowptr[base + 3] = excl + v0 + v1 + v2;
}

__global__ void k_scanB(const int* __restrict__ bsum, int* __restrict__ boff) {
    __shared__ int sD[128];
    int t = threadIdx.x;  // 128 threads
    int v = (t < SCAN_BLOCKS) ? bsum[t] : 0;
    sD[t] = v;
    __syncthreads();
    for (int off = 1; off < 128; off <<= 1) {
        int add = (t >= off) ? sD[t - off] : 0;
        __syncthreads();
        sD[t] += add;
        __syncthreads();
    }
    boff[t] = sD[t] - v;
}

__global__ __launch_bounds__(256) void k_scanC(int* __restrict__ rowptr,
                                               const int* __restrict__ boff) {
    int t = threadIdx.x;
    int base = blockIdx.x * 1024 + t * 4;
    int add = boff[blockIdx.x];
    if (base + 0 < N_NODES) rowptr[base + 0] += add;
    if (base + 1 < N_NODES) rowptr[base + 1] += add;
    if (base + 2 < N_NODES) rowptr[base + 2] += add;
    if (base + 3 < N_NODES) rowptr[base + 3] += add;
}

// ---------------- CSR fill: rowptr doubles as cursor (shift trick) --------
// After this kernel rowptr[t] == start(t+1); gather uses rowptr[wid-1].
__global__ __launch_bounds__(256) void k_fill(const int* __restrict__ ei,
                                              int* __restrict__ rowptr,
                                              int* __restrict__ csr) {
    int e = blockIdx.x * 256 + threadIdx.x;
    if (e < N_EDGES) {
        int s = ei[e];
        int t = ei[N_EDGES + e];
        int pos = atomicAdd(&rowptr[t], 1);
        csr[pos] = s;
    }
}

// ---------------- gather-mean, D=64: one wave per node ----------------
__global__ __launch_bounds__(256) void k_gather64(const float* __restrict__ x,
                                                  const int* __restrict__ rowptr,
                                                  const int* __restrict__ csr,
                                                  float* __restrict__ agg) {
    int wid = (blockIdx.x * 256 + threadIdx.x) >> 6;  // node
    int lane = threadIdx.x & 63;
    if (wid >= N_NODES) return;
    int rs = (wid > 0) ? rowptr[wid - 1] : 0;
    int re = rowptr[wid];
    float a0 = 0.f, a1 = 0.f, a2 = 0.f, a3 = 0.f;
    for (int base = rs; base < re; base += 64) {
        int j = base + lane;
        int idx = (j < re) ? csr[j] : 0;
        int cnt = min(64, re - base);
        int k = 0;
        for (; k + 4 <= cnt; k += 4) {
            int s0 = __shfl(idx, k + 0);
            int s1 = __shfl(idx, k + 1);
            int s2 = __shfl(idx, k + 2);
            int s3 = __shfl(idx, k + 3);
            a0 += x[(size_t)s0 * 64 + lane];
            a1 += x[(size_t)s1 * 64 + lane];
            a2 += x[(size_t)s2 * 64 + lane];
            a3 += x[(size_t)s3 * 64 + lane];
        }
        for (; k < cnt; ++k) {
            int s = __shfl(idx, k);
            a0 += x[(size_t)s * 64 + lane];
        }
    }
    float acc = (a0 + a1) + (a2 + a3);
    float invd = 1.0f / fmaxf((float)(re - rs), 1.0f);
    agg[(size_t)wid * 64 + lane] = acc * invd;
}

// ---------------- gather-mean, D=32: one wave per node, 2 edge-halves ------
__global__ __launch_bounds__(256) void k_gather32(const float* __restrict__ z,
                                                  const int* __restrict__ rowptr,
                                                  const int* __restrict__ csr,
                                                  float* __restrict__ agg) {
    int wid = (blockIdx.x * 256 + threadIdx.x) >> 6;  // node
    int lane = threadIdx.x & 63;
    int h = lane >> 5, o = lane & 31;
    if (wid >= N_NODES) return;
    int rs = (wid > 0) ? rowptr[wid - 1] : 0;
    int re = rowptr[wid];
    float a0 = 0.f, a1 = 0.f;
    for (int base = rs; base < re; base += 64) {
        int j = base + lane;
        int idx = (j < re) ? csr[j] : 0;
        int cnt = re - base;
        int k0 = h * 32;
        int k1 = min(cnt, k0 + 32);
        int k = k0;
        for (; k + 2 <= k1; k += 2) {
            int s0 = __shfl(idx, k + 0);
            int s1 = __shfl(idx, k + 1);
            a0 += z[(size_t)s0 * 32 + o];
            a1 += z[(size_t)s1 * 32 + o];
        }
        for (; k < k1; ++k) {
            int s = __shfl(idx, k);
            a0 += z[(size_t)s * 32 + o];
        }
    }
    float acc = a0 + a1;
    acc += __shfl_xor(acc, 32);
    if (h == 0) {
        float invd = 1.0f / fmaxf((float)(re - rs), 1.0f);
        agg[(size_t)wid * 32 + o] = acc * invd;
    }
}

// ------------- SAGE transform 64->64, register weights + readlane ----------
template <bool RELU>
__global__ __launch_bounds__(256, 2) void k_xform64(const float* __restrict__ x,
                                                    const float* __restrict__ agg,
                                                    const float* __restrict__ Wl,
                                                    const float* __restrict__ b,
                                                    const float* __restrict__ Wr,
                                                    float* __restrict__ out) {
    int lane = threadIdx.x & 63;
    int wv = (blockIdx.x * 256 + threadIdx.x) >> 6;
    int nw = gridDim.x * 4;
    float wl[64], wr[64];
#pragma unroll
    for (int f = 0; f < 64; ++f) {
        wl[f] = Wl[f * 64 + lane];
        wr[f] = Wr[f * 64 + lane];
    }
    float breg = b[lane];
    for (int node = wv; node < N_NODES; node += nw) {
        float a = agg[(size_t)node * 64 + lane];
        float xr = x[(size_t)node * 64 + lane];
        float acc0 = breg, acc1 = 0.f;
#pragma unroll
        for (int f = 0; f < 64; ++f) {
            acc0 = fmaf(bcast(a, f), wl[f], acc0);
            acc1 = fmaf(bcast(xr, f), wr[f], acc1);
        }
        float v = acc0 + acc1;
        float ss = v * v;
#pragma unroll
        for (int m = 32; m; m >>= 1) ss += __shfl_xor(ss, m);
        float o = v / fmaxf(sqrtf(ss), 1e-12f);
        if (RELU) o = fmaxf(o, 0.0f);
        out[(size_t)node * 64 + lane] = o;
    }
}

// ------------- pre-transform layer3: z = x @ W3l (64 -> 32) -------------
// Half-split: lane covers f-half (lane>>5) of output col (lane&31); 32 regs.
__global__ __launch_bounds__(256, 2) void k_pretrans(const float* __restrict__ x,
                                                     const float* __restrict__ W,
                                                     float* __restrict__ z) {
    int lane = threadIdx.x & 63;
    int o = lane & 31;
    int h = lane >> 5;
    int wv = (blockIdx.x * 256 + threadIdx.x) >> 6;
    int nw = gridDim.x * 4;
    float wc[32];
#pragma unroll
    for (int j = 0; j < 32; ++j) wc[j] = W[(h * 32 + j) * 32 + o];
    for (int node = wv; node < N_NODES; node += nw) {
        float xr = x[(size_t)node * 64 + lane];
        float acc = 0.f;
#pragma unroll
        for (int j = 0; j < 32; ++j) {
            float blo = bcast(xr, j);
            float bhi = bcast(xr, j + 32);
            acc = fmaf(h ? bhi : blo, wc[j], acc);
        }
        acc += __shfl_xor(acc, 32);
        if (lane < 32) z[(size_t)node * 32 + o] = acc;
    }
}

// ------------- layer3 finalize: out = normalize(agg32 + b + x @ W3r) -------
__global__ __launch_bounds__(256, 2) void k_fin3(const float* __restrict__ x,
                                                 const float* __restrict__ agg32,
                                                 const float* __restrict__ b,
                                                 const float* __restrict__ Wr,
                                                 float* __restrict__ out) {
    int lane = threadIdx.x & 63;
    int o = lane & 31;
    int h = lane >> 5;
    int wv = (blockIdx.x * 256 + threadIdx.x) >> 6;
    int nw = gridDim.x * 4;
    float wc[32];
#pragma unroll
    for (int j = 0; j < 32; ++j) wc[j] = Wr[(h * 32 + j) * 32 + o];
    float breg = b[o];
    for (int node = wv; node < N_NODES; node += nw) {
        float xr = x[(size_t)node * 64 + lane];
        float acc = 0.f;
#pragma unroll
        for (int j = 0; j < 32; ++j) {
            float blo = bcast(xr, j);
            float bhi = bcast(xr, j + 32);
            acc = fmaf(h ? bhi : blo, wc[j], acc);
        }
        acc += __shfl_xor(acc, 32);
        float val = acc + agg32[(size_t)node * 32 + o] + breg;
        float ss = val * val;
#pragma unroll
        for (int m = 16; m; m >>= 1) ss += __shfl_xor(ss, m);
        if (lane < 32) out[(size_t)node * 32 + o] = val / fmaxf(sqrtf(ss), 1e-12f);
    }
}

// ------------- column sum of h3 [N,32] -------------
__global__ __launch_bounds__(256) void k_colsum(const float* __restrict__ h,
                                                float* __restrict__ colsum) {
    int gid = blockIdx.x * 256 + threadIdx.x;
    const int total = N_NODES * 32;
    const int stride = 1024 * 256;
    float s = 0.0f;
    for (int i = gid; i < total; i += stride) s += h[i];
    s += __shfl_xor(s, 32);
    __shared__ float sP[4][32];
    int wave = threadIdx.x >> 6, lane = threadIdx.x & 63;
    if (lane < 32) sP[wave][lane] = s;
    __syncthreads();
    if (threadIdx.x < 32) {
        float v = sP[0][threadIdx.x] + sP[1][threadIdx.x] + sP[2][threadIdx.x] +
                  sP[3][threadIdx.x];
        atomicAdd(&colsum[threadIdx.x], v);
    }
}

// ------------- attention pool with fused context ----------------
__global__ __launch_bounds__(256) void k_attpool(const float* __restrict__ h,
                                                 const float* __restrict__ colsum,
                                                 const float* __restrict__ Watt,
                                                 float* __restrict__ pooled) {
    __shared__ float sC[32];
    __shared__ float sP[32];
    int t = threadIdx.x;
    if (t < 32) {
        float acc = 0.0f;
#pragma unroll
        for (int f = 0; f < 32; ++f)
            acc += (colsum[f] * (1.0f / N_NODES)) * Watt[f * 32 + t];
        sC[t] = tanhf(acc);
        sP[t] = 0.0f;
    }
    __syncthreads();
    int n = blockIdx.x * 256 + t;
    if (n < N_NODES) {
        const float4* row = reinterpret_cast<const float4*>(h + (size_t)n * 32);
        float4 r[8];
        float dot = 0.0f;
#pragma unroll
        for (int q = 0; q < 8; ++q) {
            r[q] = row[q];
            dot += r[q].x * sC[q * 4] + r[q].y * sC[q * 4 + 1] +
                   r[q].z * sC[q * 4 + 2] + r[q].w * sC[q * 4 + 3];
        }
        float att = 1.0f / (1.0f + expf(-dot));
#pragma unroll
        for (int q = 0; q < 8; ++q) {
            atomicAdd(&sP[q * 4 + 0], att * r[q].x);
            atomicAdd(&sP[q * 4 + 1], att * r[q].y);
            atomicAdd(&sP[q * 4 + 2], att * r[q].z);
            atomicAdd(&sP[q * 4 + 3], att * r[q].w);
        }
    }
    __syncthreads();
    if (t < 32) atomicAdd(&pooled[t], sP[t]);
}

__global__ void k_head(const float* __restrict__ pooled,
                       const float* __restrict__ Wfc, const float* __restrict__ bfc,
                       const float* __restrict__ Ws, const float* __restrict__ bs,
                       float* __restrict__ out) {
    __shared__ float sH[16];
    int t = threadIdx.x;  // 64 threads
    if (t < 16) {
        float acc = bfc[t];
#pragma unroll
        for (int f = 0; f < 32; ++f) acc += pooled[f] * Wfc[f * 16 + t];
        sH[t] = fmaxf(acc, 0.0f);
    }
    __syncthreads();
    if (t == 0) {
        float s = bs[0];
#pragma unroll
        for (int j = 0; j < 16; ++j) s += sH[j] * Ws[j];
        out[0] = 1.0f / (1.0f + expf(-s));
    }
}

extern "C" void kernel_launch(void* const* d_in, const int* in_sizes, int n_in,
                              void* d_out, int out_size, void* d_ws, size_t ws_size,
                              hipStream_t stream) {
    const float* feat = (const float*)d_in[0];
    const int* ei = (const int*)d_in[1];
    const float* W1l = (const float*)d_in[2];
    const float* b1 = (const float*)d_in[3];
    const float* W1r = (const float*)d_in[4];
    const float* W2l = (const float*)d_in[5];
    const float* b2 = (const float*)d_in[6];
    const float* W2r = (const float*)d_in[7];
    const float* W3l = (const float*)d_in[8];
    const float* b3 = (const float*)d_in[9];
    const float* W3r = (const float*)d_in[10];
    const float* Watt = (const float*)d_in[11];
    const float* Wfc = (const float*)d_in[12];
    const float* bfc = (const float*)d_in[13];
    const float* Ws = (const float*)d_in[14];
    const float* bs = (const float*)d_in[15];
    float* out = (float*)d_out;

    // ---- workspace layout (4-byte units) ----
    int* rowptr = (int*)d_ws;                 // 100000 (doubles as counts+cursor)
    int* bsum = rowptr + 100000;              // 128
    int* boff = bsum + 128;                   // 128
    int* csr = boff + 128;                    // 1,600,000
    float* bufA = (float*)(csr + N_EDGES);    // N*64
    float* bufB = bufA + (size_t)N_NODES * 64;  // N*64
    float* colsum = bufB + (size_t)N_NODES * 64;  // 32
    float* pooled = colsum + 32;                  // 32
    int* counts = (int*)(pooled + 32);            // 100000 (scratch for histogram)

    // ---- CSR build ----
    hipMemsetAsync(counts, 0, N_NODES * sizeof(int), stream);
    hipMemsetAsync(colsum, 0, 64 * sizeof(float), stream);
    k_count<<<N_EDGES / 256, 256, 0, stream>>>(ei + N_EDGES, counts);
    k_scanA<<<SCAN_BLOCKS, 256, 0, stream>>>(counts, rowptr, bsum);
    k_scanB<<<1, 128, 0, stream>>>(bsum, boff);
    k_scanC<<<SCAN_BLOCKS, 256, 0, stream>>>(rowptr, boff);
    k_fill<<<N_EDGES / 256, 256, 0, stream>>>(ei, rowptr, csr);
    // after k_fill: rowptr[t] == end of row t (start of row t+1)

    // ---- layer 1: gather feat -> bufA; xform -> h1 = bufB ----
    k_gather64<<<25000, 256, 0, stream>>>(feat, rowptr, csr, bufA);
    k_xform64<true><<<1024, 256, 0, stream>>>(feat, bufA, W1l, b1, W1r, bufB);

    // ---- layer 2: gather h1 -> bufA; xform (in-place) -> h2 = bufA ----
    k_gather64<<<25000, 256, 0, stream>>>(bufB, rowptr, csr, bufA);
    k_xform64<true><<<1024, 256, 0, stream>>>(bufB, bufA, W2l, b2, W2r, bufA);

    // ---- layer 3: pretrans h2 -> z; gather32 -> agg32; finalize -> h3 ----
    float* z = bufB;
    float* agg32 = bufB + (size_t)N_NODES * 32;
    k_pretrans<<<1024, 256, 0, stream>>>(bufA, W3l, z);
    k_gather32<<<25000, 256, 0, stream>>>(z, rowptr, csr, agg32);
    k_fin3<<<1024, 256, 0, stream>>>(bufA, agg32, b3, W3r, z);

    // ---- attention pooling + head (h3 = bufB[0:N*32]) ----
    k_colsum<<<1024, 256, 0, stream>>>(bufB, colsum);
    k_attpool<<<(N_NODES + 255) / 256, 256, 0, stream>>>(bufB, colsum, Watt, pooled);
    k_head<<<1, 64, 0, stream>>>(pooled, Wfc, bfc, Ws, bs, out);
}

// Round 5
// 708.208 us; speedup vs baseline: 5.5151x; 1.0844x over previous
//
#include <hip/hip_runtime.h>
#include <hip/hip_bf16.h>
#include <math.h>

#define N_NODES 100000
#define N_EDGES 1600000
#define SCAN_BLOCKS 98   // ceil(100000/1024)
#define XCD_RANGE 12500  // N_NODES / 8

__device__ __forceinline__ float bcast(float v, int l) {
    return __int_as_float(__builtin_amdgcn_readlane(__float_as_int(v), l));
}

// ---------------- histogram of targets (int) ----------------
__global__ __launch_bounds__(256) void k_count(const int* __restrict__ tgt,
                                               int* __restrict__ counts) {
    int e = blockIdx.x * 256 + threadIdx.x;
    if (e < N_EDGES) atomicAdd(&counts[tgt[e]], 1);
}

// ---------------- block-local exclusive scan (1024/block) ----------------
__global__ __launch_bounds__(256) void k_scanA(const int* __restrict__ counts,
                                               int* __restrict__ rowptr,
                                               int* __restrict__ bsum) {
    int t = threadIdx.x;
    int base = blockIdx.x * 1024 + t * 4;
    int v0 = (base + 0 < N_NODES) ? counts[base + 0] : 0;
    int v1 = (base + 1 < N_NODES) ? counts[base + 1] : 0;
    int v2 = (base + 2 < N_NODES) ? counts[base + 2] : 0;
    int v3 = (base + 3 < N_NODES) ? counts[base + 3] : 0;
    int s = v0 + v1 + v2 + v3;
    __shared__ int sS[256];
    sS[t] = s;
    __syncthreads();
    for (int off = 1; off < 256; off <<= 1) {
        int add = (t >= off) ? sS[t - off] : 0;
        __syncthreads();
        sS[t] += add;
        __syncthreads();
    }
    int excl = sS[t] - s;
    if (t == 255) bsum[blockIdx.x] = sS[255];
    if (base + 0 < N_NODES) rowptr[base + 0] = excl;
    if (base + 1 < N_NODES) rowptr[base + 1] = excl + v0;
    if (base + 2 < N_NODES) rowptr[base + 2] = excl + v0 + v1;
    if (base + 3 < N_NODES) rowptr[base + 3] = excl + v0 + v1 + v2;
}

__global__ void k_scanB(const int* __restrict__ bsum, int* __restrict__ boff) {
    __shared__ int sD[128];
    int t = threadIdx.x;  // 128 threads
    int v = (t < SCAN_BLOCKS) ? bsum[t] : 0;
    sD[t] = v;
    __syncthreads();
    for (int off = 1; off < 128; off <<= 1) {
        int add = (t >= off) ? sD[t - off] : 0;
        __syncthreads();
        sD[t] += add;
        __syncthreads();
    }
    boff[t] = sD[t] - v;
}

__global__ __launch_bounds__(256) void k_scanC(int* __restrict__ rowptr,
                                               const int* __restrict__ boff) {
    int t = threadIdx.x;
    int base = blockIdx.x * 1024 + t * 4;
    int add = boff[blockIdx.x];
    if (base + 0 < N_NODES) rowptr[base + 0] += add;
    if (base + 1 < N_NODES) rowptr[base + 1] += add;
    if (base + 2 < N_NODES) rowptr[base + 2] += add;
    if (base + 3 < N_NODES) rowptr[base + 3] += add;
}

// ---------------- CSR fill, XCD-partitioned ----------------
// Block b handles edge chunk (b>>3) but ONLY targets in range (b&7)*12500..
// blockIdx%8 == XCD id (round-robin dispatch), so each XCD's csr writes stay
// in a 0.8 MB slice that fits its private L2 -> writebacks ~= compulsory.
// rowptr doubles as cursor: after this kernel rowptr[t] == start(t+1).
__global__ __launch_bounds__(256) void k_fill(const int* __restrict__ ei,
                                              int* __restrict__ rowptr,
                                              int* __restrict__ csr) {
    int p = blockIdx.x & 7;
    int e = (blockIdx.x >> 3) * 256 + threadIdx.x;
    int t = ei[N_EDGES + e];
    if ((unsigned)(t - p * XCD_RANGE) < XCD_RANGE) {
        int s = ei[e];
        int pos = atomicAdd(&rowptr[t], 1);
        csr[pos] = s;
    }
}

// ---------------- gather-mean D=64: wave/node, float4 lanes, 16 rows MLP ---
// lane = sub*16 + q : sub (0..3) = neighbor slot, q*4 = feature offset.
// One load instruction fetches 4 neighbor rows; 4 chains -> 16 rows in flight.
__global__ __launch_bounds__(256) void k_gather64(const float* __restrict__ x,
                                                  const int* __restrict__ rowptr,
                                                  const int* __restrict__ csr,
                                                  float* __restrict__ agg) {
    int wid = (blockIdx.x * 256 + threadIdx.x) >> 6;  // node
    int lane = threadIdx.x & 63;
    if (wid >= N_NODES) return;
    int rs = (wid > 0) ? rowptr[wid - 1] : 0;
    int re = rowptr[wid];
    int sub = lane >> 4;
    int c4 = (lane & 15) * 4;
    float4 a0 = {0, 0, 0, 0}, a1 = {0, 0, 0, 0}, a2 = {0, 0, 0, 0},
           a3 = {0, 0, 0, 0};
#define GADD64(A, N)                                                          \
    {                                                                         \
        int n_ = (N);                                                         \
        int s_ = __shfl(idx, n_);                                             \
        float4 v_ = *reinterpret_cast<const float4*>(x + (size_t)s_ * 64 + c4); \
        float m_ = (n_ < cnt) ? 1.0f : 0.0f;                                  \
        A.x = fmaf(v_.x, m_, A.x);                                            \
        A.y = fmaf(v_.y, m_, A.y);                                            \
        A.z = fmaf(v_.z, m_, A.z);                                            \
        A.w = fmaf(v_.w, m_, A.w);                                            \
    }
    for (int base = rs; base < re; base += 64) {
        int j = base + lane;
        int idx = (j < re) ? csr[j] : 0;
        int cnt = min(64, re - base);
#pragma unroll
        for (int g = 0; g < 4; ++g) {
            if (g * 16 < cnt) {  // wave-uniform
                GADD64(a0, g * 16 + 0 + sub);
                GADD64(a1, g * 16 + 4 + sub);
                GADD64(a2, g * 16 + 8 + sub);
                GADD64(a3, g * 16 + 12 + sub);
            }
        }
    }
#undef GADD64
    float4 acc;
    acc.x = (a0.x + a1.x) + (a2.x + a3.x);
    acc.y = (a0.y + a1.y) + (a2.y + a3.y);
    acc.z = (a0.z + a1.z) + (a2.z + a3.z);
    acc.w = (a0.w + a1.w) + (a2.w + a3.w);
    acc.x += __shfl_xor(acc.x, 16); acc.x += __shfl_xor(acc.x, 32);
    acc.y += __shfl_xor(acc.y, 16); acc.y += __shfl_xor(acc.y, 32);
    acc.z += __shfl_xor(acc.z, 16); acc.z += __shfl_xor(acc.z, 32);
    acc.w += __shfl_xor(acc.w, 16); acc.w += __shfl_xor(acc.w, 32);
    if (lane < 16) {
        float invd = 1.0f / fmaxf((float)(re - rs), 1.0f);
        float4 r = {acc.x * invd, acc.y * invd, acc.z * invd, acc.w * invd};
        *reinterpret_cast<float4*>(agg + (size_t)wid * 64 + c4) = r;
    }
}

// ---------------- gather-mean D=32: wave/node, 8 slots, 32 rows MLP --------
__global__ __launch_bounds__(256) void k_gather32(const float* __restrict__ z,
                                                  const int* __restrict__ rowptr,
                                                  const int* __restrict__ csr,
                                                  float* __restrict__ agg) {
    int wid = (blockIdx.x * 256 + threadIdx.x) >> 6;  // node
    int lane = threadIdx.x & 63;
    if (wid >= N_NODES) return;
    int rs = (wid > 0) ? rowptr[wid - 1] : 0;
    int re = rowptr[wid];
    int sub = lane >> 3;
    int c4 = (lane & 7) * 4;
    float4 a0 = {0, 0, 0, 0}, a1 = {0, 0, 0, 0}, a2 = {0, 0, 0, 0},
           a3 = {0, 0, 0, 0};
#define GADD32(A, N)                                                          \
    {                                                                         \
        int n_ = (N);                                                         \
        int s_ = __shfl(idx, n_);                                             \
        float4 v_ = *reinterpret_cast<const float4*>(z + (size_t)s_ * 32 + c4); \
        float m_ = (n_ < cnt) ? 1.0f : 0.0f;                                  \
        A.x = fmaf(v_.x, m_, A.x);                                            \
        A.y = fmaf(v_.y, m_, A.y);                                            \
        A.z = fmaf(v_.z, m_, A.z);                                            \
        A.w = fmaf(v_.w, m_, A.w);                                            \
    }
    for (int base = rs; base < re; base += 64) {
        int j = base + lane;
        int idx = (j < re) ? csr[j] : 0;
        int cnt = min(64, re - base);
#pragma unroll
        for (int g = 0; g < 2; ++g) {
            if (g * 32 < cnt) {  // wave-uniform
                GADD32(a0, g * 32 + 0 + sub);
                GADD32(a1, g * 32 + 8 + sub);
                GADD32(a2, g * 32 + 16 + sub);
                GADD32(a3, g * 32 + 24 + sub);
            }
        }
    }
#undef GADD32
    float4 acc;
    acc.x = (a0.x + a1.x) + (a2.x + a3.x);
    acc.y = (a0.y + a1.y) + (a2.y + a3.y);
    acc.z = (a0.z + a1.z) + (a2.z + a3.z);
    acc.w = (a0.w + a1.w) + (a2.w + a3.w);
#pragma unroll
    for (int m = 8; m <= 32; m <<= 1) {
        acc.x += __shfl_xor(acc.x, m);
        acc.y += __shfl_xor(acc.y, m);
        acc.z += __shfl_xor(acc.z, m);
        acc.w += __shfl_xor(acc.w, m);
    }
    if (lane < 8) {
        float invd = 1.0f / fmaxf((float)(re - rs), 1.0f);
        float4 r = {acc.x * invd, acc.y * invd, acc.z * invd, acc.w * invd};
        *reinterpret_cast<float4*>(agg + (size_t)wid * 32 + c4) = r;
    }
}

// ------------- SAGE transform 64->64, register weights + readlane ----------
template <bool RELU>
__global__ __launch_bounds__(256, 2) void k_xform64(const float* __restrict__ x,
                                                    const float* __restrict__ agg,
                                                    const float* __restrict__ Wl,
                                                    const float* __restrict__ b,
                                                    const float* __restrict__ Wr,
                                                    float* __restrict__ out) {
    int lane = threadIdx.x & 63;
    int wv = (blockIdx.x * 256 + threadIdx.x) >> 6;
    int nw = gridDim.x * 4;
    float wl[64], wr[64];
#pragma unroll
    for (int f = 0; f < 64; ++f) {
        wl[f] = Wl[f * 64 + lane];
        wr[f] = Wr[f * 64 + lane];
    }
    float breg = b[lane];
    for (int node = wv; node < N_NODES; node += nw) {
        float a = agg[(size_t)node * 64 + lane];
        float xr = x[(size_t)node * 64 + lane];
        float acc0 = breg, acc1 = 0.f;
#pragma unroll
        for (int f = 0; f < 64; ++f) {
            acc0 = fmaf(bcast(a, f), wl[f], acc0);
            acc1 = fmaf(bcast(xr, f), wr[f], acc1);
        }
        float v = acc0 + acc1;
        float ss = v * v;
#pragma unroll
        for (int m = 32; m; m >>= 1) ss += __shfl_xor(ss, m);
        float o = v / fmaxf(sqrtf(ss), 1e-12f);
        if (RELU) o = fmaxf(o, 0.0f);
        out[(size_t)node * 64 + lane] = o;
    }
}

// ------------- pre-transform layer3: z = x @ W3l (64 -> 32) -------------
__global__ __launch_bounds__(256, 2) void k_pretrans(const float* __restrict__ x,
                                                     const float* __restrict__ W,
                                                     float* __restrict__ z) {
    int lane = threadIdx.x & 63;
    int o = lane & 31;
    int h = lane >> 5;
    int wv = (blockIdx.x * 256 + threadIdx.x) >> 6;
    int nw = gridDim.x * 4;
    float wc[32];
#pragma unroll
    for (int j = 0; j < 32; ++j) wc[j] = W[(h * 32 + j) * 32 + o];
    for (int node = wv; node < N_NODES; node += nw) {
        float xr = x[(size_t)node * 64 + lane];
        float acc = 0.f;
#pragma unroll
        for (int j = 0; j < 32; ++j) {
            float blo = bcast(xr, j);
            float bhi = bcast(xr, j + 32);
            acc = fmaf(h ? bhi : blo, wc[j], acc);
        }
        acc += __shfl_xor(acc, 32);
        if (lane < 32) z[(size_t)node * 32 + o] = acc;
    }
}

// ------------- layer3 finalize: out = normalize(agg32 + b + x @ W3r) -------
__global__ __launch_bounds__(256, 2) void k_fin3(const float* __restrict__ x,
                                                 const float* __restrict__ agg32,
                                                 const float* __restrict__ b,
                                                 const float* __restrict__ Wr,
                                                 float* __restrict__ out) {
    int lane = threadIdx.x & 63;
    int o = lane & 31;
    int h = lane >> 5;
    int wv = (blockIdx.x * 256 + threadIdx.x) >> 6;
    int nw = gridDim.x * 4;
    float wc[32];
#pragma unroll
    for (int j = 0; j < 32; ++j) wc[j] = Wr[(h * 32 + j) * 32 + o];
    float breg = b[o];
    for (int node = wv; node < N_NODES; node += nw) {
        float xr = x[(size_t)node * 64 + lane];
        float acc = 0.f;
#pragma unroll
        for (int j = 0; j < 32; ++j) {
            float blo = bcast(xr, j);
            float bhi = bcast(xr, j + 32);
            acc = fmaf(h ? bhi : blo, wc[j], acc);
        }
        acc += __shfl_xor(acc, 32);
        float val = acc + agg32[(size_t)node * 32 + o] + breg;
        float ss = val * val;
#pragma unroll
        for (int m = 16; m; m >>= 1) ss += __shfl_xor(ss, m);
        if (lane < 32) out[(size_t)node * 32 + o] = val / fmaxf(sqrtf(ss), 1e-12f);
    }
}

// ------------- column sum of h3 [N,32] -------------
__global__ __launch_bounds__(256) void k_colsum(const float* __restrict__ h,
                                                float* __restrict__ colsum) {
    int gid = blockIdx.x * 256 + threadIdx.x;
    const int total = N_NODES * 32;
    const int stride = 1024 * 256;
    float s = 0.0f;
    for (int i = gid; i < total; i += stride) s += h[i];
    s += __shfl_xor(s, 32);
    __shared__ float sP[4][32];
    int wave = threadIdx.x >> 6, lane = threadIdx.x & 63;
    if (lane < 32) sP[wave][lane] = s;
    __syncthreads();
    if (threadIdx.x < 32) {
        float v = sP[0][threadIdx.x] + sP[1][threadIdx.x] + sP[2][threadIdx.x] +
                  sP[3][threadIdx.x];
        atomicAdd(&colsum[threadIdx.x], v);
    }
}

// ------------- attention pool with fused context ----------------
__global__ __launch_bounds__(256) void k_attpool(const float* __restrict__ h,
                                                 const float* __restrict__ colsum,
                                                 const float* __restrict__ Watt,
                                                 float* __restrict__ pooled) {
    __shared__ float sC[32];
    __shared__ float sP[32];
    int t = threadIdx.x;
    if (t < 32) {
        float acc = 0.0f;
#pragma unroll
        for (int f = 0; f < 32; ++f)
            acc += (colsum[f] * (1.0f / N_NODES)) * Watt[f * 32 + t];
        sC[t] = tanhf(acc);
        sP[t] = 0.0f;
    }
    __syncthreads();
    int n = blockIdx.x * 256 + t;
    if (n < N_NODES) {
        const float4* row = reinterpret_cast<const float4*>(h + (size_t)n * 32);
        float4 r[8];
        float dot = 0.0f;
#pragma unroll
        for (int q = 0; q < 8; ++q) {
            r[q] = row[q];
            dot += r[q].x * sC[q * 4] + r[q].y * sC[q * 4 + 1] +
                   r[q].z * sC[q * 4 + 2] + r[q].w * sC[q * 4 + 3];
        }
        float att = 1.0f / (1.0f + expf(-dot));
#pragma unroll
        for (int q = 0; q < 8; ++q) {
            atomicAdd(&sP[q * 4 + 0], att * r[q].x);
            atomicAdd(&sP[q * 4 + 1], att * r[q].y);
            atomicAdd(&sP[q * 4 + 2], att * r[q].z);
            atomicAdd(&sP[q * 4 + 3], att * r[q].w);
        }
    }
    __syncthreads();
    if (t < 32) atomicAdd(&pooled[t], sP[t]);
}

__global__ void k_head(const float* __restrict__ pooled,
                       const float* __restrict__ Wfc, const float* __restrict__ bfc,
                       const float* __restrict__ Ws, const float* __restrict__ bs,
                       float* __restrict__ out) {
    __shared__ float sH[16];
    int t = threadIdx.x;  // 64 threads
    if (t < 16) {
        float acc = bfc[t];
#pragma unroll
        for (int f = 0; f < 32; ++f) acc += pooled[f] * Wfc[f * 16 + t];
        sH[t] = fmaxf(acc, 0.0f);
    }
    __syncthreads();
    if (t == 0) {
        float s = bs[0];
#pragma unroll
        for (int j = 0; j < 16; ++j) s += sH[j] * Ws[j];
        out[0] = 1.0f / (1.0f + expf(-s));
    }
}

extern "C" void kernel_launch(void* const* d_in, const int* in_sizes, int n_in,
                              void* d_out, int out_size, void* d_ws, size_t ws_size,
                              hipStream_t stream) {
    const float* feat = (const float*)d_in[0];
    const int* ei = (const int*)d_in[1];
    const float* W1l = (const float*)d_in[2];
    const float* b1 = (const float*)d_in[3];
    const float* W1r = (const float*)d_in[4];
    const float* W2l = (const float*)d_in[5];
    const float* b2 = (const float*)d_in[6];
    const float* W2r = (const float*)d_in[7];
    const float* W3l = (const float*)d_in[8];
    const float* b3 = (const float*)d_in[9];
    const float* W3r = (const float*)d_in[10];
    const float* Watt = (const float*)d_in[11];
    const float* Wfc = (const float*)d_in[12];
    const float* bfc = (const float*)d_in[13];
    const float* Ws = (const float*)d_in[14];
    const float* bs = (const float*)d_in[15];
    float* out = (float*)d_out;

    // ---- workspace layout (4-byte units) ----
    int* rowptr = (int*)d_ws;                 // 100000 (doubles as cursor)
    int* bsum = rowptr + 100000;              // 128
    int* boff = bsum + 128;                   // 128
    int* csr = boff + 128;                    // 1,600,000
    float* bufA = (float*)(csr + N_EDGES);    // N*64
    float* bufB = bufA + (size_t)N_NODES * 64;  // N*64
    float* colsum = bufB + (size_t)N_NODES * 64;  // 32
    float* pooled = colsum + 32;                  // 32
    int* counts = (int*)(pooled + 32);            // 100000 (histogram scratch)

    // ---- CSR build ----
    hipMemsetAsync(counts, 0, N_NODES * sizeof(int), stream);
    hipMemsetAsync(colsum, 0, 64 * sizeof(float), stream);
    k_count<<<N_EDGES / 256, 256, 0, stream>>>(ei + N_EDGES, counts);
    k_scanA<<<SCAN_BLOCKS, 256, 0, stream>>>(counts, rowptr, bsum);
    k_scanB<<<1, 128, 0, stream>>>(bsum, boff);
    k_scanC<<<SCAN_BLOCKS, 256, 0, stream>>>(rowptr, boff);
    k_fill<<<(N_EDGES / 256) * 8, 256, 0, stream>>>(ei, rowptr, csr);
    // after k_fill: rowptr[t] == end of row t (start of row t+1)

    // ---- layer 1: gather feat -> bufA; xform -> h1 = bufB ----
    k_gather64<<<25000, 256, 0, stream>>>(feat, rowptr, csr, bufA);
    k_xform64<true><<<1024, 256, 0, stream>>>(feat, bufA, W1l, b1, W1r, bufB);

    // ---- layer 2: gather h1 -> bufA; xform (in-place) -> h2 = bufA ----
    k_gather64<<<25000, 256, 0, stream>>>(bufB, rowptr, csr, bufA);
    k_xform64<true><<<1024, 256, 0, stream>>>(bufB, bufA, W2l, b2, W2r, bufA);

    // ---- layer 3: pretrans h2 -> z; gather32 -> agg32; finalize -> h3 ----
    float* z = bufB;
    float* agg32 = bufB + (size_t)N_NODES * 32;
    k_pretrans<<<1024, 256, 0, stream>>>(bufA, W3l, z);
    k_gather32<<<25000, 256, 0, stream>>>(z, rowptr, csr, agg32);
    k_fin3<<<1024, 256, 0, stream>>>(bufA, agg32, b3, W3r, z);

    // ---- attention pooling + head (h3 = bufB[0:N*32]) ----
    k_colsum<<<1024, 256, 0, stream>>>(bufB, colsum);
    k_attpool<<<(N_NODES + 255) / 256, 256, 0, stream>>>(bufB, colsum, Watt, pooled);
    k_head<<<1, 64, 0, stream>>>(pooled, Wfc, bfc, Ws, bs, out);
}

// Round 6
// 682.026 us; speedup vs baseline: 5.7268x; 1.0384x over previous
//
#include <hip/hip_runtime.h>
#include <hip/hip_bf16.h>
#include <hip/hip_fp16.h>
#include <math.h>

#define N_NODES 100000
#define N_EDGES 1600000
#define SCAN_BLOCKS 98   // ceil(100000/1024)
#define XCD_RANGE 12500  // N_NODES / 8

typedef _Float16 h8 __attribute__((ext_vector_type(8)));

__device__ __forceinline__ float bcast(float v, int l) {
    return __int_as_float(__builtin_amdgcn_readlane(__float_as_int(v), l));
}

// ---------------- fp32 -> fp16 convert (8 elems/thread) ----------------
__global__ __launch_bounds__(256) void k_cvt(const float* __restrict__ in,
                                             _Float16* __restrict__ out) {
    int i = blockIdx.x * 256 + threadIdx.x;  // 800000 threads
    const float4* p = reinterpret_cast<const float4*>(in) + (size_t)i * 2;
    float4 u = p[0], v = p[1];
    h8 o;
    o[0] = u.x; o[1] = u.y; o[2] = u.z; o[3] = u.w;
    o[4] = v.x; o[5] = v.y; o[6] = v.z; o[7] = v.w;
    *(reinterpret_cast<h8*>(out) + i) = o;
}

// ---------------- histogram of targets (int) ----------------
__global__ __launch_bounds__(256) void k_count(const int* __restrict__ tgt,
                                               int* __restrict__ counts) {
    int e = blockIdx.x * 256 + threadIdx.x;
    if (e < N_EDGES) atomicAdd(&counts[tgt[e]], 1);
}

// ---------------- block-local exclusive scan (1024/block) ----------------
__global__ __launch_bounds__(256) void k_scanA(const int* __restrict__ counts,
                                               int* __restrict__ rowptr,
                                               int* __restrict__ bsum) {
    int t = threadIdx.x;
    int base = blockIdx.x * 1024 + t * 4;
    int v0 = (base + 0 < N_NODES) ? counts[base + 0] : 0;
    int v1 = (base + 1 < N_NODES) ? counts[base + 1] : 0;
    int v2 = (base + 2 < N_NODES) ? counts[base + 2] : 0;
    int v3 = (base + 3 < N_NODES) ? counts[base + 3] : 0;
    int s = v0 + v1 + v2 + v3;
    __shared__ int sS[256];
    sS[t] = s;
    __syncthreads();
    for (int off = 1; off < 256; off <<= 1) {
        int add = (t >= off) ? sS[t - off] : 0;
        __syncthreads();
        sS[t] += add;
        __syncthreads();
    }
    int excl = sS[t] - s;
    if (t == 255) bsum[blockIdx.x] = sS[255];
    if (base + 0 < N_NODES) rowptr[base + 0] = excl;
    if (base + 1 < N_NODES) rowptr[base + 1] = excl + v0;
    if (base + 2 < N_NODES) rowptr[base + 2] = excl + v0 + v1;
    if (base + 3 < N_NODES) rowptr[base + 3] = excl + v0 + v1 + v2;
}

__global__ void k_scanB(const int* __restrict__ bsum, int* __restrict__ boff) {
    __shared__ int sD[128];
    int t = threadIdx.x;  // 128 threads
    int v = (t < SCAN_BLOCKS) ? bsum[t] : 0;
    sD[t] = v;
    __syncthreads();
    for (int off = 1; off < 128; off <<= 1) {
        int add = (t >= off) ? sD[t - off] : 0;
        __syncthreads();
        sD[t] += add;
        __syncthreads();
    }
    boff[t] = sD[t] - v;
}

__global__ __launch_bounds__(256) void k_scanC(int* __restrict__ rowptr,
                                               const int* __restrict__ boff) {
    int t = threadIdx.x;
    int base = blockIdx.x * 1024 + t * 4;
    int add = boff[blockIdx.x];
    if (base + 0 < N_NODES) rowptr[base + 0] += add;
    if (base + 1 < N_NODES) rowptr[base + 1] += add;
    if (base + 2 < N_NODES) rowptr[base + 2] += add;
    if (base + 3 < N_NODES) rowptr[base + 3] += add;
}

// ---------------- CSR fill, XCD-partitioned ----------------
__global__ __launch_bounds__(256) void k_fill(const int* __restrict__ ei,
                                              int* __restrict__ rowptr,
                                              int* __restrict__ csr) {
    int p = blockIdx.x & 7;
    int e = (blockIdx.x >> 3) * 256 + threadIdx.x;
    int t = ei[N_EDGES + e];
    if ((unsigned)(t - p * XCD_RANGE) < XCD_RANGE) {
        int s = ei[e];
        int pos = atomicAdd(&rowptr[t], 1);
        csr[pos] = s;
    }
}

// ---------------- fp16 row accumulate: 8 rows per wave-load ----------------
template <int LD>
__device__ __forceinline__ void gadd(float (&A)[8], const _Float16* __restrict__ x,
                                     int idx, int n, int cnt, int c8) {
    int s = __shfl(idx, n);
    h8 v = *reinterpret_cast<const h8*>(x + (size_t)s * LD + c8);
    float m = (n < cnt) ? 1.0f : 0.0f;
#pragma unroll
    for (int j = 0; j < 8; ++j) A[j] = fmaf((float)v[j], m, A[j]);
}

// ---------------- gather-mean D=64 (fp16 in/out, fp32 accum) --------------
// lane = sub*8 + q : sub (0..7) = row slot, q*8 = col offset (8 halves/lane).
__global__ __launch_bounds__(256) void k_gather64(const _Float16* __restrict__ x,
                                                  const int* __restrict__ rowptr,
                                                  const int* __restrict__ csr,
                                                  _Float16* __restrict__ agg) {
    int wid = (blockIdx.x * 256 + threadIdx.x) >> 6;  // node
    int lane = threadIdx.x & 63;
    if (wid >= N_NODES) return;
    int rs = (wid > 0) ? rowptr[wid - 1] : 0;
    int re = rowptr[wid];
    int sub = lane >> 3;
    int c8 = (lane & 7) * 8;
    float a0[8] = {0}, a1[8] = {0}, a2[8] = {0}, a3[8] = {0};
    for (int base = rs; base < re; base += 64) {
        int j = base + lane;
        int idx = (j < re) ? csr[j] : 0;
        int cnt = min(64, re - base);
        // 2 loads per 16 rows; guards are wave-uniform
        {
            gadd<64>(a0, x, idx, 0 + sub, cnt, c8);
            gadd<64>(a1, x, idx, 8 + sub, cnt, c8);
        }
        if (16 < cnt) {
            gadd<64>(a2, x, idx, 16 + sub, cnt, c8);
            gadd<64>(a3, x, idx, 24 + sub, cnt, c8);
        }
        if (32 < cnt) {
            gadd<64>(a0, x, idx, 32 + sub, cnt, c8);
            gadd<64>(a1, x, idx, 40 + sub, cnt, c8);
        }
        if (48 < cnt) {
            gadd<64>(a2, x, idx, 48 + sub, cnt, c8);
            gadd<64>(a3, x, idx, 56 + sub, cnt, c8);
        }
    }
    float acc[8];
#pragma unroll
    for (int j = 0; j < 8; ++j) acc[j] = (a0[j] + a1[j]) + (a2[j] + a3[j]);
#pragma unroll
    for (int m = 8; m <= 32; m <<= 1) {
#pragma unroll
        for (int j = 0; j < 8; ++j) acc[j] += __shfl_xor(acc[j], m);
    }
    if (lane < 8) {
        float invd = 1.0f / fmaxf((float)(re - rs), 1.0f);
        h8 o;
#pragma unroll
        for (int j = 0; j < 8; ++j) o[j] = (_Float16)(acc[j] * invd);
        *reinterpret_cast<h8*>(agg + (size_t)wid * 64 + c8) = o;
    }
}

// ---------------- gather-mean D=32 (fp16 in/out): 16 rows per wave-load ----
__global__ __launch_bounds__(256) void k_gather32(const _Float16* __restrict__ z,
                                                  const int* __restrict__ rowptr,
                                                  const int* __restrict__ csr,
                                                  _Float16* __restrict__ agg) {
    int wid = (blockIdx.x * 256 + threadIdx.x) >> 6;  // node
    int lane = threadIdx.x & 63;
    if (wid >= N_NODES) return;
    int rs = (wid > 0) ? rowptr[wid - 1] : 0;
    int re = rowptr[wid];
    int sub = lane >> 2;
    int c8 = (lane & 3) * 8;
    float a0[8] = {0}, a1[8] = {0}, a2[8] = {0}, a3[8] = {0};
    for (int base = rs; base < re; base += 64) {
        int j = base + lane;
        int idx = (j < re) ? csr[j] : 0;
        int cnt = min(64, re - base);
        gadd<32>(a0, z, idx, 0 + sub, cnt, c8);
        if (16 < cnt) gadd<32>(a1, z, idx, 16 + sub, cnt, c8);
        if (32 < cnt) gadd<32>(a2, z, idx, 32 + sub, cnt, c8);
        if (48 < cnt) gadd<32>(a3, z, idx, 48 + sub, cnt, c8);
    }
    float acc[8];
#pragma unroll
    for (int j = 0; j < 8; ++j) acc[j] = (a0[j] + a1[j]) + (a2[j] + a3[j]);
#pragma unroll
    for (int m = 4; m <= 32; m <<= 1) {
#pragma unroll
        for (int j = 0; j < 8; ++j) acc[j] += __shfl_xor(acc[j], m);
    }
    if (lane < 4) {
        float invd = 1.0f / fmaxf((float)(re - rs), 1.0f);
        h8 o;
#pragma unroll
        for (int j = 0; j < 8; ++j) o[j] = (_Float16)(acc[j] * invd);
        *reinterpret_cast<h8*>(agg + (size_t)wid * 32 + c8) = o;
    }
}

// ------------- SAGE transform 64->64, register weights + readlane ----------
template <bool RELU>
__global__ __launch_bounds__(256, 2) void k_xform64(const _Float16* __restrict__ x,
                                                    const _Float16* __restrict__ agg,
                                                    const float* __restrict__ Wl,
                                                    const float* __restrict__ b,
                                                    const float* __restrict__ Wr,
                                                    _Float16* __restrict__ out) {
    int lane = threadIdx.x & 63;
    int wv = (blockIdx.x * 256 + threadIdx.x) >> 6;
    int nw = gridDim.x * 4;
    float wl[64], wr[64];
#pragma unroll
    for (int f = 0; f < 64; ++f) {
        wl[f] = Wl[f * 64 + lane];
        wr[f] = Wr[f * 64 + lane];
    }
    float breg = b[lane];
    for (int node = wv; node < N_NODES; node += nw) {
        float a = (float)agg[(size_t)node * 64 + lane];
        float xr = (float)x[(size_t)node * 64 + lane];
        float acc0 = breg, acc1 = 0.f;
#pragma unroll
        for (int f = 0; f < 64; ++f) {
            acc0 = fmaf(bcast(a, f), wl[f], acc0);
            acc1 = fmaf(bcast(xr, f), wr[f], acc1);
        }
        float v = acc0 + acc1;
        float ss = v * v;
#pragma unroll
        for (int m = 32; m; m >>= 1) ss += __shfl_xor(ss, m);
        float o = v / fmaxf(sqrtf(ss), 1e-12f);
        if (RELU) o = fmaxf(o, 0.0f);
        out[(size_t)node * 64 + lane] = (_Float16)o;
    }
}

// ------------- pre-transform layer3: z = x @ W3l (64 -> 32), fp16 ----------
__global__ __launch_bounds__(256, 2) void k_pretrans(const _Float16* __restrict__ x,
                                                     const float* __restrict__ W,
                                                     _Float16* __restrict__ z) {
    int lane = threadIdx.x & 63;
    int o = lane & 31;
    int h = lane >> 5;
    int wv = (blockIdx.x * 256 + threadIdx.x) >> 6;
    int nw = gridDim.x * 4;
    float wc[32];
#pragma unroll
    for (int j = 0; j < 32; ++j) wc[j] = W[(h * 32 + j) * 32 + o];
    for (int node = wv; node < N_NODES; node += nw) {
        float xr = (float)x[(size_t)node * 64 + lane];
        float acc = 0.f;
#pragma unroll
        for (int j = 0; j < 32; ++j) {
            float blo = bcast(xr, j);
            float bhi = bcast(xr, j + 32);
            acc = fmaf(h ? bhi : blo, wc[j], acc);
        }
        acc += __shfl_xor(acc, 32);
        if (lane < 32) z[(size_t)node * 32 + o] = (_Float16)acc;
    }
}

// ------------- layer3 finalize: out = normalize(agg32 + b + x @ W3r) -------
__global__ __launch_bounds__(256, 2) void k_fin3(const _Float16* __restrict__ x,
                                                 const _Float16* __restrict__ agg32,
                                                 const float* __restrict__ b,
                                                 const float* __restrict__ Wr,
                                                 float* __restrict__ out) {
    int lane = threadIdx.x & 63;
    int o = lane & 31;
    int h = lane >> 5;
    int wv = (blockIdx.x * 256 + threadIdx.x) >> 6;
    int nw = gridDim.x * 4;
    float wc[32];
#pragma unroll
    for (int j = 0; j < 32; ++j) wc[j] = Wr[(h * 32 + j) * 32 + o];
    float breg = b[o];
    for (int node = wv; node < N_NODES; node += nw) {
        float xr = (float)x[(size_t)node * 64 + lane];
        float acc = 0.f;
#pragma unroll
        for (int j = 0; j < 32; ++j) {
            float blo = bcast(xr, j);
            float bhi = bcast(xr, j + 32);
            acc = fmaf(h ? bhi : blo, wc[j], acc);
        }
        acc += __shfl_xor(acc, 32);
        float val = acc + (float)agg32[(size_t)node * 32 + o] + breg;
        float ss = val * val;
#pragma unroll
        for (int m = 16; m; m >>= 1) ss += __shfl_xor(ss, m);
        if (lane < 32) out[(size_t)node * 32 + o] = val / fmaxf(sqrtf(ss), 1e-12f);
    }
}

// ------------- column sum of h3 [N,32] -------------
__global__ __launch_bounds__(256) void k_colsum(const float* __restrict__ h,
                                                float* __restrict__ colsum) {
    int gid = blockIdx.x * 256 + threadIdx.x;
    const int total = N_NODES * 32;
    const int stride = 1024 * 256;
    float s = 0.0f;
    for (int i = gid; i < total; i += stride) s += h[i];
    s += __shfl_xor(s, 32);
    __shared__ float sP[4][32];
    int wave = threadIdx.x >> 6, lane = threadIdx.x & 63;
    if (lane < 32) sP[wave][lane] = s;
    __syncthreads();
    if (threadIdx.x < 32) {
        float v = sP[0][threadIdx.x] + sP[1][threadIdx.x] + sP[2][threadIdx.x] +
                  sP[3][threadIdx.x];
        atomicAdd(&colsum[threadIdx.x], v);
    }
}

// ------------- attention pool with fused context ----------------
__global__ __launch_bounds__(256) void k_attpool(const float* __restrict__ h,
                                                 const float* __restrict__ colsum,
                                                 const float* __restrict__ Watt,
                                                 float* __restrict__ pooled) {
    __shared__ float sC[32];
    __shared__ float sP[32];
    int t = threadIdx.x;
    if (t < 32) {
        float acc = 0.0f;
#pragma unroll
        for (int f = 0; f < 32; ++f)
            acc += (colsum[f] * (1.0f / N_NODES)) * Watt[f * 32 + t];
        sC[t] = tanhf(acc);
        sP[t] = 0.0f;
    }
    __syncthreads();
    int n = blockIdx.x * 256 + t;
    if (n < N_NODES) {
        const float4* row = reinterpret_cast<const float4*>(h + (size_t)n * 32);
        float4 r[8];
        float dot = 0.0f;
#pragma unroll
        for (int q = 0; q < 8; ++q) {
            r[q] = row[q];
            dot += r[q].x * sC[q * 4] + r[q].y * sC[q * 4 + 1] +
                   r[q].z * sC[q * 4 + 2] + r[q].w * sC[q * 4 + 3];
        }
        float att = 1.0f / (1.0f + expf(-dot));
#pragma unroll
        for (int q = 0; q < 8; ++q) {
            atomicAdd(&sP[q * 4 + 0], att * r[q].x);
            atomicAdd(&sP[q * 4 + 1], att * r[q].y);
            atomicAdd(&sP[q * 4 + 2], att * r[q].z);
            atomicAdd(&sP[q * 4 + 3], att * r[q].w);
        }
    }
    __syncthreads();
    if (t < 32) atomicAdd(&pooled[t], sP[t]);
}

__global__ void k_head(const float* __restrict__ pooled,
                       const float* __restrict__ Wfc, const float* __restrict__ bfc,
                       const float* __restrict__ Ws, const float* __restrict__ bs,
                       float* __restrict__ out) {
    __shared__ float sH[16];
    int t = threadIdx.x;  // 64 threads
    if (t < 16) {
        float acc = bfc[t];
#pragma unroll
        for (int f = 0; f < 32; ++f) acc += pooled[f] * Wfc[f * 16 + t];
        sH[t] = fmaxf(acc, 0.0f);
    }
    __syncthreads();
    if (t == 0) {
        float s = bs[0];
#pragma unroll
        for (int j = 0; j < 16; ++j) s += sH[j] * Ws[j];
        out[0] = 1.0f / (1.0f + expf(-s));
    }
}

extern "C" void kernel_launch(void* const* d_in, const int* in_sizes, int n_in,
                              void* d_out, int out_size, void* d_ws, size_t ws_size,
                              hipStream_t stream) {
    const float* feat = (const float*)d_in[0];
    const int* ei = (const int*)d_in[1];
    const float* W1l = (const float*)d_in[2];
    const float* b1 = (const float*)d_in[3];
    const float* W1r = (const float*)d_in[4];
    const float* W2l = (const float*)d_in[5];
    const float* b2 = (const float*)d_in[6];
    const float* W2r = (const float*)d_in[7];
    const float* W3l = (const float*)d_in[8];
    const float* b3 = (const float*)d_in[9];
    const float* W3r = (const float*)d_in[10];
    const float* Watt = (const float*)d_in[11];
    const float* Wfc = (const float*)d_in[12];
    const float* bfc = (const float*)d_in[13];
    const float* Ws = (const float*)d_in[14];
    const float* bs = (const float*)d_in[15];
    float* out = (float*)d_out;

    // ---- workspace layout ----
    int* rowptr = (int*)d_ws;                    // 100000 (doubles as cursor)
    int* bsum = rowptr + 100000;                 // 128
    int* boff = bsum + 128;                      // 128
    int* counts = boff + 128;                    // 100000
    int* csr = counts + 100000;                  // 1,600,000
    _Float16* B1 = (_Float16*)(csr + N_EDGES);   // 6.4M halves (12.8 MB)
    _Float16* B2 = B1 + (size_t)N_NODES * 64;    // 6.4M halves
    _Float16* B3 = B2 + (size_t)N_NODES * 64;    // 6.4M halves
    float* h3 = (float*)(B3 + (size_t)N_NODES * 64);  // N*32 fp32
    float* colsum = h3 + (size_t)N_NODES * 32;        // 32
    float* pooled = colsum + 32;                      // 32

    // ---- CSR build + feat convert ----
    hipMemsetAsync(counts, 0, N_NODES * sizeof(int), stream);
    hipMemsetAsync(colsum, 0, 64 * sizeof(float), stream);
    k_cvt<<<3125, 256, 0, stream>>>(feat, B1);  // featH = B1
    k_count<<<N_EDGES / 256, 256, 0, stream>>>(ei + N_EDGES, counts);
    k_scanA<<<SCAN_BLOCKS, 256, 0, stream>>>(counts, rowptr, bsum);
    k_scanB<<<1, 128, 0, stream>>>(bsum, boff);
    k_scanC<<<SCAN_BLOCKS, 256, 0, stream>>>(rowptr, boff);
    k_fill<<<(N_EDGES / 256) * 8, 256, 0, stream>>>(ei, rowptr, csr);
    // after k_fill: rowptr[t] == end of row t

    // ---- layer 1: gather featH -> B2; xform(featH,B2) -> h1 = B3 ----
    k_gather64<<<25000, 256, 0, stream>>>(B1, rowptr, csr, B2);
    k_xform64<true><<<1024, 256, 0, stream>>>(B1, B2, W1l, b1, W1r, B3);

    // ---- layer 2: gather h1 -> B2; xform(h1,B2) -> h2 = B1 ----
    k_gather64<<<25000, 256, 0, stream>>>(B3, rowptr, csr, B2);
    k_xform64<true><<<1024, 256, 0, stream>>>(B3, B2, W2l, b2, W2r, B1);

    // ---- layer 3: pretrans h2 -> z = B3lo; gather32 -> B3hi; fin3 -> h3 ----
    _Float16* z = B3;
    _Float16* agg32 = B3 + (size_t)N_NODES * 32;
    k_pretrans<<<1024, 256, 0, stream>>>(B1, W3l, z);
    k_gather32<<<25000, 256, 0, stream>>>(z, rowptr, csr, agg32);
    k_fin3<<<1024, 256, 0, stream>>>(B1, agg32, b3, W3r, h3);

    // ---- attention pooling + head ----
    k_colsum<<<1024, 256, 0, stream>>>(h3, colsum);
    k_attpool<<<(N_NODES + 255) / 256, 256, 0, stream>>>(h3, colsum, Watt, pooled);
    k_head<<<1, 64, 0, stream>>>(pooled, Wfc, bfc, Ws, bs, out);
}

// Round 8
// 599.292 us; speedup vs baseline: 6.5174x; 1.1381x over previous
//
#include <hip/hip_runtime.h>
#include <hip/hip_bf16.h>
#include <hip/hip_fp16.h>
#include <math.h>

#define N_NODES 100000
#define N_EDGES 1600000
#define SCAN_BLOCKS 98   // ceil(100000/1024)
#define XCD_RANGE 12500  // N_NODES / 8

typedef _Float16 h8 __attribute__((ext_vector_type(8)));
typedef float f32x4 __attribute__((ext_vector_type(4)));

__device__ __forceinline__ float bcast(float v, int l) {
    return __int_as_float(__builtin_amdgcn_readlane(__float_as_int(v), l));
}

// ---------------- fp32 -> fp16 convert (8 elems/thread) ----------------
__global__ __launch_bounds__(256) void k_cvt(const float* __restrict__ in,
                                             _Float16* __restrict__ out) {
    int i = blockIdx.x * 256 + threadIdx.x;  // 800000 threads
    const f32x4* p = reinterpret_cast<const f32x4*>(in) + (size_t)i * 2;
    f32x4 u = __builtin_nontemporal_load(p);
    f32x4 v = __builtin_nontemporal_load(p + 1);
    h8 o;
    o[0] = u[0]; o[1] = u[1]; o[2] = u[2]; o[3] = u[3];
    o[4] = v[0]; o[5] = v[1]; o[6] = v[2]; o[7] = v[3];
    *(reinterpret_cast<h8*>(out) + i) = o;
}

// ---------------- histogram of targets (int) ----------------
__global__ __launch_bounds__(256) void k_count(const int* __restrict__ tgt,
                                               int* __restrict__ counts) {
    int e = blockIdx.x * 256 + threadIdx.x;
    if (e < N_EDGES) atomicAdd(&counts[__builtin_nontemporal_load(tgt + e)], 1);
}

// ---------------- block-local exclusive scan (1024/block) ----------------
__global__ __launch_bounds__(256) void k_scanA(const int* __restrict__ counts,
                                               int* __restrict__ rowptr,
                                               int* __restrict__ bsum) {
    int t = threadIdx.x;
    int base = blockIdx.x * 1024 + t * 4;
    int v0 = (base + 0 < N_NODES) ? counts[base + 0] : 0;
    int v1 = (base + 1 < N_NODES) ? counts[base + 1] : 0;
    int v2 = (base + 2 < N_NODES) ? counts[base + 2] : 0;
    int v3 = (base + 3 < N_NODES) ? counts[base + 3] : 0;
    int s = v0 + v1 + v2 + v3;
    __shared__ int sS[256];
    sS[t] = s;
    __syncthreads();
    for (int off = 1; off < 256; off <<= 1) {
        int add = (t >= off) ? sS[t - off] : 0;
        __syncthreads();
        sS[t] += add;
        __syncthreads();
    }
    int excl = sS[t] - s;
    if (t == 255) bsum[blockIdx.x] = sS[255];
    if (base + 0 < N_NODES) rowptr[base + 0] = excl;
    if (base + 1 < N_NODES) rowptr[base + 1] = excl + v0;
    if (base + 2 < N_NODES) rowptr[base + 2] = excl + v0 + v1;
    if (base + 3 < N_NODES) rowptr[base + 3] = excl + v0 + v1 + v2;
}

__global__ void k_scanB(const int* __restrict__ bsum, int* __restrict__ boff) {
    __shared__ int sD[128];
    int t = threadIdx.x;  // 128 threads
    int v = (t < SCAN_BLOCKS) ? bsum[t] : 0;
    sD[t] = v;
    __syncthreads();
    for (int off = 1; off < 128; off <<= 1) {
        int add = (t >= off) ? sD[t - off] : 0;
        __syncthreads();
        sD[t] += add;
        __syncthreads();
    }
    boff[t] = sD[t] - v;
}

__global__ __launch_bounds__(256) void k_scanC(int* __restrict__ rowptr,
                                               const int* __restrict__ boff) {
    int t = threadIdx.x;
    int base = blockIdx.x * 1024 + t * 4;
    int add = boff[blockIdx.x];
    if (base + 0 < N_NODES) rowptr[base + 0] += add;
    if (base + 1 < N_NODES) rowptr[base + 1] += add;
    if (base + 2 < N_NODES) rowptr[base + 2] += add;
    if (base + 3 < N_NODES) rowptr[base + 3] += add;
}

// ---------------- CSR fill, XCD-partitioned, NT edge reads ----------------
__global__ __launch_bounds__(256) void k_fill(const int* __restrict__ ei,
                                              int* __restrict__ rowptr,
                                              int* __restrict__ csr) {
    int p = blockIdx.x & 7;
    int e = (blockIdx.x >> 3) * 256 + threadIdx.x;
    int t = __builtin_nontemporal_load(ei + N_EDGES + e);
    if ((unsigned)(t - p * XCD_RANGE) < XCD_RANGE) {
        int s = __builtin_nontemporal_load(ei + e);
        int pos = atomicAdd(&rowptr[t], 1);
        csr[pos] = s;
    }
}

// ---------------- fp16 row accumulate: 8 rows per wave-load ----------------
template <int LD>
__device__ __forceinline__ void gadd(float (&A)[8], const _Float16* __restrict__ x,
                                     int idx, int n, int cnt, int c8) {
    int s = __shfl(idx, n);
    h8 v = *reinterpret_cast<const h8*>(x + (size_t)s * LD + c8);
    float m = (n < cnt) ? 1.0f : 0.0f;
#pragma unroll
    for (int j = 0; j < 8; ++j) A[j] = fmaf((float)v[j], m, A[j]);
}

// ---------------- gather-mean D=64 (fp16 in/out, fp32 accum) --------------
__global__ __launch_bounds__(256) void k_gather64(const _Float16* __restrict__ x,
                                                  const int* __restrict__ rowptr,
                                                  const int* __restrict__ csr,
                                                  _Float16* __restrict__ agg) {
    int wid = (blockIdx.x * 256 + threadIdx.x) >> 6;  // node
    int lane = threadIdx.x & 63;
    if (wid >= N_NODES) return;
    int rs = (wid > 0) ? rowptr[wid - 1] : 0;
    int re = rowptr[wid];
    int sub = lane >> 3;
    int c8 = (lane & 7) * 8;
    float a0[8] = {0}, a1[8] = {0}, a2[8] = {0}, a3[8] = {0};
    for (int base = rs; base < re; base += 64) {
        int j = base + lane;
        int idx = (j < re) ? __builtin_nontemporal_load(csr + j) : 0;
        int cnt = min(64, re - base);
        {
            gadd<64>(a0, x, idx, 0 + sub, cnt, c8);
            gadd<64>(a1, x, idx, 8 + sub, cnt, c8);
        }
        if (16 < cnt) {
            gadd<64>(a2, x, idx, 16 + sub, cnt, c8);
            gadd<64>(a3, x, idx, 24 + sub, cnt, c8);
        }
        if (32 < cnt) {
            gadd<64>(a0, x, idx, 32 + sub, cnt, c8);
            gadd<64>(a1, x, idx, 40 + sub, cnt, c8);
        }
        if (48 < cnt) {
            gadd<64>(a2, x, idx, 48 + sub, cnt, c8);
            gadd<64>(a3, x, idx, 56 + sub, cnt, c8);
        }
    }
    float acc[8];
#pragma unroll
    for (int j = 0; j < 8; ++j) acc[j] = (a0[j] + a1[j]) + (a2[j] + a3[j]);
#pragma unroll
    for (int m = 8; m <= 32; m <<= 1) {
#pragma unroll
        for (int j = 0; j < 8; ++j) acc[j] += __shfl_xor(acc[j], m);
    }
    if (lane < 8) {
        float invd = 1.0f / fmaxf((float)(re - rs), 1.0f);
        h8 o;
#pragma unroll
        for (int j = 0; j < 8; ++j) o[j] = (_Float16)(acc[j] * invd);
        *reinterpret_cast<h8*>(agg + (size_t)wid * 64 + c8) = o;
    }
}

// ---------------- gather-mean D=32 (fp16 in/out): 16 rows per wave-load ----
__global__ __launch_bounds__(256) void k_gather32(const _Float16* __restrict__ z,
                                                  const int* __restrict__ rowptr,
                                                  const int* __restrict__ csr,
                                                  _Float16* __restrict__ agg) {
    int wid = (blockIdx.x * 256 + threadIdx.x) >> 6;  // node
    int lane = threadIdx.x & 63;
    if (wid >= N_NODES) return;
    int rs = (wid > 0) ? rowptr[wid - 1] : 0;
    int re = rowptr[wid];
    int sub = lane >> 2;
    int c8 = (lane & 3) * 8;
    float a0[8] = {0}, a1[8] = {0}, a2[8] = {0}, a3[8] = {0};
    for (int base = rs; base < re; base += 64) {
        int j = base + lane;
        int idx = (j < re) ? __builtin_nontemporal_load(csr + j) : 0;
        int cnt = min(64, re - base);
        gadd<32>(a0, z, idx, 0 + sub, cnt, c8);
        if (16 < cnt) gadd<32>(a1, z, idx, 16 + sub, cnt, c8);
        if (32 < cnt) gadd<32>(a2, z, idx, 32 + sub, cnt, c8);
        if (48 < cnt) gadd<32>(a3, z, idx, 48 + sub, cnt, c8);
    }
    float acc[8];
#pragma unroll
    for (int j = 0; j < 8; ++j) acc[j] = (a0[j] + a1[j]) + (a2[j] + a3[j]);
#pragma unroll
    for (int m = 4; m <= 32; m <<= 1) {
#pragma unroll
        for (int j = 0; j < 8; ++j) acc[j] += __shfl_xor(acc[j], m);
    }
    if (lane < 4) {
        float invd = 1.0f / fmaxf((float)(re - rs), 1.0f);
        h8 o;
#pragma unroll
        for (int j = 0; j < 8; ++j) o[j] = (_Float16)(acc[j] * invd);
        *reinterpret_cast<h8*>(agg + (size_t)wid * 32 + c8) = o;
    }
}

// ------------- SAGE transform 64->64 via MFMA 16x16x32 f16 -----------------
// Per 16-node tile: out[16,64] = normalize(agg[16,64]@Wl + b + x[16,64]@Wr).
// A frag: lane l holds A[l&15][(l>>4)*8 + kt*32 + 0..7] (contiguous h8).
// B frag: lane l holds W[(kt*32+(l>>4)*8+j)*64 + ct*16 + (l&15)].
// C/D:   col = l&15, row = (l>>4)*4 + reg   [verified gfx950 mapping]
template <bool RELU>
__global__ __launch_bounds__(256) void k_xform64m(const _Float16* __restrict__ x,
                                                  const _Float16* __restrict__ agg,
                                                  const float* __restrict__ Wl,
                                                  const float* __restrict__ b,
                                                  const float* __restrict__ Wr,
                                                  _Float16* __restrict__ out) {
    int lane = threadIdx.x & 63;
    int g = lane >> 4;   // k-group / row-group
    int r = lane & 15;   // A-row, C-col
    int wv = (blockIdx.x * 256 + threadIdx.x) >> 6;
    int nw = gridDim.x * 4;
    h8 wl[2][4], wr[2][4];
#pragma unroll
    for (int kt = 0; kt < 2; ++kt)
#pragma unroll
        for (int ct = 0; ct < 4; ++ct)
#pragma unroll
            for (int j = 0; j < 8; ++j) {
                int row = kt * 32 + g * 8 + j, col = ct * 16 + r;
                wl[kt][ct][j] = (_Float16)Wl[row * 64 + col];
                wr[kt][ct][j] = (_Float16)Wr[row * 64 + col];
            }
    float biasv[4];
#pragma unroll
    for (int ct = 0; ct < 4; ++ct) biasv[ct] = b[ct * 16 + r];
    for (int tile = wv; tile < N_NODES / 16; tile += nw) {
        int n0 = tile * 16;
        const h8* arow = reinterpret_cast<const h8*>(agg + (size_t)(n0 + r) * 64);
        const h8* xrow = reinterpret_cast<const h8*>(x + (size_t)(n0 + r) * 64);
        h8 aa0 = arow[g], aa1 = arow[4 + g];
        h8 ax0 = xrow[g], ax1 = xrow[4 + g];
        f32x4 acc[4];
#pragma unroll
        for (int ct = 0; ct < 4; ++ct) {
            acc[ct] = (f32x4){biasv[ct], biasv[ct], biasv[ct], biasv[ct]};
            acc[ct] = __builtin_amdgcn_mfma_f32_16x16x32_f16(aa0, wl[0][ct], acc[ct], 0, 0, 0);
            acc[ct] = __builtin_amdgcn_mfma_f32_16x16x32_f16(aa1, wl[1][ct], acc[ct], 0, 0, 0);
            acc[ct] = __builtin_amdgcn_mfma_f32_16x16x32_f16(ax0, wr[0][ct], acc[ct], 0, 0, 0);
            acc[ct] = __builtin_amdgcn_mfma_f32_16x16x32_f16(ax1, wr[1][ct], acc[ct], 0, 0, 0);
        }
#pragma unroll
        for (int reg = 0; reg < 4; ++reg) {
            float ss = acc[0][reg] * acc[0][reg] + acc[1][reg] * acc[1][reg] +
                       acc[2][reg] * acc[2][reg] + acc[3][reg] * acc[3][reg];
            ss += __shfl_xor(ss, 1);
            ss += __shfl_xor(ss, 2);
            ss += __shfl_xor(ss, 4);
            ss += __shfl_xor(ss, 8);
            float rinv = 1.0f / fmaxf(sqrtf(ss), 1e-12f);
            int row = n0 + g * 4 + reg;
#pragma unroll
            for (int ct = 0; ct < 4; ++ct) {
                float v = acc[ct][reg] * rinv;
                if (RELU) v = fmaxf(v, 0.0f);
                out[(size_t)row * 64 + ct * 16 + r] = (_Float16)v;
            }
        }
    }
}

// ------------- pre-transform layer3: z = x @ W3l (64 -> 32), fp16 ----------
__global__ __launch_bounds__(256, 2) void k_pretrans(const _Float16* __restrict__ x,
                                                     const float* __restrict__ W,
                                                     _Float16* __restrict__ z) {
    int lane = threadIdx.x & 63;
    int o = lane & 31;
    int h = lane >> 5;
    int wv = (blockIdx.x * 256 + threadIdx.x) >> 6;
    int nw = gridDim.x * 4;
    float wc[32];
#pragma unroll
    for (int j = 0; j < 32; ++j) wc[j] = W[(h * 32 + j) * 32 + o];
    for (int node = wv; node < N_NODES; node += nw) {
        float xr = (float)x[(size_t)node * 64 + lane];
        float acc = 0.f;
#pragma unroll
        for (int j = 0; j < 32; ++j) {
            float blo = bcast(xr, j);
            float bhi = bcast(xr, j + 32);
            acc = fmaf(h ? bhi : blo, wc[j], acc);
        }
        acc += __shfl_xor(acc, 32);
        if (lane < 32) z[(size_t)node * 32 + o] = (_Float16)acc;
    }
}

// ------------- layer3 finalize: out = normalize(agg32 + b + x @ W3r) -------
__global__ __launch_bounds__(256, 2) void k_fin3(const _Float16* __restrict__ x,
                                                 const _Float16* __restrict__ agg32,
                                                 const float* __restrict__ b,
                                                 const float* __restrict__ Wr,
                                                 float* __restrict__ out) {
    int lane = threadIdx.x & 63;
    int o = lane & 31;
    int h = lane >> 5;
    int wv = (blockIdx.x * 256 + threadIdx.x) >> 6;
    int nw = gridDim.x * 4;
    float wc[32];
#pragma unroll
    for (int j = 0; j < 32; ++j) wc[j] = Wr[(h * 32 + j) * 32 + o];
    float breg = b[o];
    for (int node = wv; node < N_NODES; node += nw) {
        float xr = (float)x[(size_t)node * 64 + lane];
        float acc = 0.f;
#pragma unroll
        for (int j = 0; j < 32; ++j) {
            float blo = bcast(xr, j);
            float bhi = bcast(xr, j + 32);
            acc = fmaf(h ? bhi : blo, wc[j], acc);
        }
        acc += __shfl_xor(acc, 32);
        float val = acc + (float)agg32[(size_t)node * 32 + o] + breg;
        float ss = val * val;
#pragma unroll
        for (int m = 16; m; m >>= 1) ss += __shfl_xor(ss, m);
        if (lane < 32) out[(size_t)node * 32 + o] = val / fmaxf(sqrtf(ss), 1e-12f);
    }
}

// ------------- column sum of h3 [N,32] -------------
__global__ __launch_bounds__(256) void k_colsum(const float* __restrict__ h,
                                                float* __restrict__ colsum) {
    int gid = blockIdx.x * 256 + threadIdx.x;
    const int total = N_NODES * 32;
    const int stride = 1024 * 256;
    float s = 0.0f;
    for (int i = gid; i < total; i += stride) s += h[i];
    s += __shfl_xor(s, 32);
    __shared__ float sP[4][32];
    int wave = threadIdx.x >> 6, lane = threadIdx.x & 63;
    if (lane < 32) sP[wave][lane] = s;
    __syncthreads();
    if (threadIdx.x < 32) {
        float v = sP[0][threadIdx.x] + sP[1][threadIdx.x] + sP[2][threadIdx.x] +
                  sP[3][threadIdx.x];
        atomicAdd(&colsum[threadIdx.x], v);
    }
}

// ------------- attention pool with fused context ----------------
__global__ __launch_bounds__(256) void k_attpool(const float* __restrict__ h,
                                                 const float* __restrict__ colsum,
                                                 const float* __restrict__ Watt,
                                                 float* __restrict__ pooled) {
    __shared__ float sC[32];
    __shared__ float sP[32];
    int t = threadIdx.x;
    if (t < 32) {
        float acc = 0.0f;
#pragma unroll
        for (int f = 0; f < 32; ++f)
            acc += (colsum[f] * (1.0f / N_NODES)) * Watt[f * 32 + t];
        sC[t] = tanhf(acc);
        sP[t] = 0.0f;
    }
    __syncthreads();
    int n = blockIdx.x * 256 + t;
    if (n < N_NODES) {
        const float4* row = reinterpret_cast<const float4*>(h + (size_t)n * 32);
        float4 r[8];
        float dot = 0.0f;
#pragma unroll
        for (int q = 0; q < 8; ++q) {
            r[q] = row[q];
            dot += r[q].x * sC[q * 4] + r[q].y * sC[q * 4 + 1] +
                   r[q].z * sC[q * 4 + 2] + r[q].w * sC[q * 4 + 3];
        }
        float att = 1.0f / (1.0f + expf(-dot));
#pragma unroll
        for (int q = 0; q < 8; ++q) {
            atomicAdd(&sP[q * 4 + 0], att * r[q].x);
            atomicAdd(&sP[q * 4 + 1], att * r[q].y);
            atomicAdd(&sP[q * 4 + 2], att * r[q].z);
            atomicAdd(&sP[q * 4 + 3], att * r[q].w);
        }
    }
    __syncthreads();
    if (t < 32) atomicAdd(&pooled[t], sP[t]);
}

__global__ void k_head(const float* __restrict__ pooled,
                       const float* __restrict__ Wfc, const float* __restrict__ bfc,
                       const float* __restrict__ Ws, const float* __restrict__ bs,
                       float* __restrict__ out) {
    __shared__ float sH[16];
    int t = threadIdx.x;  // 64 threads
    if (t < 16) {
        float acc = bfc[t];
#pragma unroll
        for (int f = 0; f < 32; ++f) acc += pooled[f] * Wfc[f * 16 + t];
        sH[t] = fmaxf(acc, 0.0f);
    }
    __syncthreads();
    if (t == 0) {
        float s = bs[0];
#pragma unroll
        for (int j = 0; j < 16; ++j) s += sH[j] * Ws[j];
        out[0] = 1.0f / (1.0f + expf(-s));
    }
}

extern "C" void kernel_launch(void* const* d_in, const int* in_sizes, int n_in,
                              void* d_out, int out_size, void* d_ws, size_t ws_size,
                              hipStream_t stream) {
    const float* feat = (const float*)d_in[0];
    const int* ei = (const int*)d_in[1];
    const float* W1l = (const float*)d_in[2];
    const float* b1 = (const float*)d_in[3];
    const float* W1r = (const float*)d_in[4];
    const float* W2l = (const float*)d_in[5];
    const float* b2 = (const float*)d_in[6];
    const float* W2r = (const float*)d_in[7];
    const float* W3l = (const float*)d_in[8];
    const float* b3 = (const float*)d_in[9];
    const float* W3r = (const float*)d_in[10];
    const float* Watt = (const float*)d_in[11];
    const float* Wfc = (const float*)d_in[12];
    const float* bfc = (const float*)d_in[13];
    const float* Ws = (const float*)d_in[14];
    const float* bs = (const float*)d_in[15];
    float* out = (float*)d_out;

    // ---- workspace layout ----
    int* rowptr = (int*)d_ws;                    // 100000 (doubles as cursor)
    int* bsum = rowptr + 100000;                 // 128
    int* boff = bsum + 128;                      // 128
    int* counts = boff + 128;                    // 100000
    int* csr = counts + 100000;                  // 1,600,000
    _Float16* B1 = (_Float16*)(csr + N_EDGES);   // 6.4M halves (12.8 MB)
    _Float16* B2 = B1 + (size_t)N_NODES * 64;    // 6.4M halves
    _Float16* B3 = B2 + (size_t)N_NODES * 64;    // 6.4M halves
    float* h3 = (float*)(B3 + (size_t)N_NODES * 64);  // N*32 fp32
    float* colsum = h3 + (size_t)N_NODES * 32;        // 32
    float* pooled = colsum + 32;                      // 32

    // ---- CSR build + feat convert ----
    hipMemsetAsync(counts, 0, N_NODES * sizeof(int), stream);
    hipMemsetAsync(colsum, 0, 64 * sizeof(float), stream);
    k_cvt<<<3125, 256, 0, stream>>>(feat, B1);  // featH = B1
    k_count<<<N_EDGES / 256, 256, 0, stream>>>(ei + N_EDGES, counts);
    k_scanA<<<SCAN_BLOCKS, 256, 0, stream>>>(counts, rowptr, bsum);
    k_scanB<<<1, 128, 0, stream>>>(bsum, boff);
    k_scanC<<<SCAN_BLOCKS, 256, 0, stream>>>(rowptr, boff);
    k_fill<<<(N_EDGES / 256) * 8, 256, 0, stream>>>(ei, rowptr, csr);
    // after k_fill: rowptr[t] == end of row t

    // ---- layer 1: gather featH -> B2; xform(featH,B2) -> h1 = B3 ----
    k_gather64<<<25000, 256, 0, stream>>>(B1, rowptr, csr, B2);
    k_xform64m<true><<<512, 256, 0, stream>>>(B1, B2, W1l, b1, W1r, B3);

    // ---- layer 2: gather h1 -> B2; xform(h1,B2) -> h2 = B1 ----
    k_gather64<<<25000, 256, 0, stream>>>(B3, rowptr, csr, B2);
    k_xform64m<true><<<512, 256, 0, stream>>>(B3, B2, W2l, b2, W2r, B1);

    // ---- layer 3: pretrans h2 -> z = B3lo; gather32 -> B3hi; fin3 -> h3 ----
    _Float16* z = B3;
    _Float16* agg32 = B3 + (size_t)N_NODES * 32;
    k_pretrans<<<1024, 256, 0, stream>>>(B1, W3l, z);
    k_gather32<<<25000, 256, 0, stream>>>(z, rowptr, csr, agg32);
    k_fin3<<<1024, 256, 0, stream>>>(B1, agg32, b3, W3r, h3);

    // ---- attention pooling + head ----
    k_colsum<<<1024, 256, 0, stream>>>(h3, colsum);
    k_attpool<<<(N_NODES + 255) / 256, 256, 0, stream>>>(h3, colsum, Watt, pooled);
    k_head<<<1, 64, 0, stream>>>(pooled, Wfc, bfc, Ws, bs, out);
}

// Round 9
// 524.012 us; speedup vs baseline: 7.4537x; 1.1437x over previous
//
#include <hip/hip_runtime.h>
#include <hip/hip_bf16.h>
#include <hip/hip_fp16.h>
#include <math.h>

#define N_NODES 100000
#define N_EDGES 1600000
#define SCAN_BLOCKS 98   // ceil(100000/1024)
#define XCD_RANGE 12500  // N_NODES / 8

typedef _Float16 h8 __attribute__((ext_vector_type(8)));
typedef float f32x4 __attribute__((ext_vector_type(4)));

__device__ __forceinline__ float bcast(float v, int l) {
    return __int_as_float(__builtin_amdgcn_readlane(__float_as_int(v), l));
}

// ---------------- fp32 -> fp16 convert (8 elems/thread) ----------------
__global__ __launch_bounds__(256) void k_cvt(const float* __restrict__ in,
                                             _Float16* __restrict__ out) {
    int i = blockIdx.x * 256 + threadIdx.x;  // 800000 threads
    const f32x4* p = reinterpret_cast<const f32x4*>(in) + (size_t)i * 2;
    f32x4 u = __builtin_nontemporal_load(p);
    f32x4 v = __builtin_nontemporal_load(p + 1);
    h8 o;
    o[0] = u[0]; o[1] = u[1]; o[2] = u[2]; o[3] = u[3];
    o[4] = v[0]; o[5] = v[1]; o[6] = v[2]; o[7] = v[3];
    *(reinterpret_cast<h8*>(out) + i) = o;
}

// ---------------- histogram of targets, XCD-partitioned ----------------
__global__ __launch_bounds__(256) void k_count(const int* __restrict__ tgt,
                                               int* __restrict__ counts) {
    int p = blockIdx.x & 7;
    int e = (blockIdx.x >> 3) * 256 + threadIdx.x;
    int t = __builtin_nontemporal_load(tgt + e);
    if ((unsigned)(t - p * XCD_RANGE) < XCD_RANGE) atomicAdd(&counts[t], 1);
}

// ---------------- block-local exclusive scan (1024/block) ----------------
__global__ __launch_bounds__(256) void k_scanA(const int* __restrict__ counts,
                                               int* __restrict__ rowptr,
                                               int* __restrict__ bsum) {
    int t = threadIdx.x;
    int base = blockIdx.x * 1024 + t * 4;
    int v0 = (base + 0 < N_NODES) ? counts[base + 0] : 0;
    int v1 = (base + 1 < N_NODES) ? counts[base + 1] : 0;
    int v2 = (base + 2 < N_NODES) ? counts[base + 2] : 0;
    int v3 = (base + 3 < N_NODES) ? counts[base + 3] : 0;
    int s = v0 + v1 + v2 + v3;
    __shared__ int sS[256];
    sS[t] = s;
    __syncthreads();
    for (int off = 1; off < 256; off <<= 1) {
        int add = (t >= off) ? sS[t - off] : 0;
        __syncthreads();
        sS[t] += add;
        __syncthreads();
    }
    int excl = sS[t] - s;
    if (t == 255) bsum[blockIdx.x] = sS[255];
    if (base + 0 < N_NODES) rowptr[base + 0] = excl;
    if (base + 1 < N_NODES) rowptr[base + 1] = excl + v0;
    if (base + 2 < N_NODES) rowptr[base + 2] = excl + v0 + v1;
    if (base + 3 < N_NODES) rowptr[base + 3] = excl + v0 + v1 + v2;
}

__global__ void k_scanB(const int* __restrict__ bsum, int* __restrict__ boff) {
    __shared__ int sD[128];
    int t = threadIdx.x;  // 128 threads
    int v = (t < SCAN_BLOCKS) ? bsum[t] : 0;
    sD[t] = v;
    __syncthreads();
    for (int off = 1; off < 128; off <<= 1) {
        int add = (t >= off) ? sD[t - off] : 0;
        __syncthreads();
        sD[t] += add;
        __syncthreads();
    }
    boff[t] = sD[t] - v;
}

__global__ __launch_bounds__(256) void k_scanC(int* __restrict__ rowptr,
                                               const int* __restrict__ boff) {
    int t = threadIdx.x;
    int base = blockIdx.x * 1024 + t * 4;
    int add = boff[blockIdx.x];
    if (base + 0 < N_NODES) rowptr[base + 0] += add;
    if (base + 1 < N_NODES) rowptr[base + 1] += add;
    if (base + 2 < N_NODES) rowptr[base + 2] += add;
    if (base + 3 < N_NODES) rowptr[base + 3] += add;
}

// ---------------- CSR fill, XCD-partitioned, NT edge reads ----------------
__global__ __launch_bounds__(256) void k_fill(const int* __restrict__ ei,
                                              int* __restrict__ rowptr,
                                              int* __restrict__ csr) {
    int p = blockIdx.x & 7;
    int e = (blockIdx.x >> 3) * 256 + threadIdx.x;
    int t = __builtin_nontemporal_load(ei + N_EDGES + e);
    if ((unsigned)(t - p * XCD_RANGE) < XCD_RANGE) {
        int s = __builtin_nontemporal_load(ei + e);
        int pos = atomicAdd(&rowptr[t], 1);
        csr[pos] = s;
    }
}

// ---------------- fp16 row accumulate: 8 rows per wave-load ----------------
template <int LD>
__device__ __forceinline__ void gadd(float (&A)[8], const _Float16* __restrict__ x,
                                     int idx, int n, int cnt, int c8) {
    int s = __shfl(idx, n);
    h8 v = *reinterpret_cast<const h8*>(x + (size_t)s * LD + c8);
    float m = (n < cnt) ? 1.0f : 0.0f;
#pragma unroll
    for (int j = 0; j < 8; ++j) A[j] = fmaf((float)v[j], m, A[j]);
}

// ---------------- gather-mean D=64 (fp16 in/out, fp32 accum) --------------
__global__ __launch_bounds__(256) void k_gather64(const _Float16* __restrict__ x,
                                                  const int* __restrict__ rowptr,
                                                  const int* __restrict__ csr,
                                                  _Float16* __restrict__ agg) {
    int wid = (blockIdx.x * 256 + threadIdx.x) >> 6;  // node
    int lane = threadIdx.x & 63;
    if (wid >= N_NODES) return;
    int rs = (wid > 0) ? rowptr[wid - 1] : 0;
    int re = rowptr[wid];
    int sub = lane >> 3;
    int c8 = (lane & 7) * 8;
    float a0[8] = {0}, a1[8] = {0}, a2[8] = {0}, a3[8] = {0};
    for (int base = rs; base < re; base += 64) {
        int j = base + lane;
        int idx = (j < re) ? csr[j] : 0;
        int cnt = min(64, re - base);
        {
            gadd<64>(a0, x, idx, 0 + sub, cnt, c8);
            gadd<64>(a1, x, idx, 8 + sub, cnt, c8);
        }
        if (16 < cnt) {
            gadd<64>(a2, x, idx, 16 + sub, cnt, c8);
            gadd<64>(a3, x, idx, 24 + sub, cnt, c8);
        }
        if (32 < cnt) {
            gadd<64>(a0, x, idx, 32 + sub, cnt, c8);
            gadd<64>(a1, x, idx, 40 + sub, cnt, c8);
        }
        if (48 < cnt) {
            gadd<64>(a2, x, idx, 48 + sub, cnt, c8);
            gadd<64>(a3, x, idx, 56 + sub, cnt, c8);
        }
    }
    float acc[8];
#pragma unroll
    for (int j = 0; j < 8; ++j) acc[j] = (a0[j] + a1[j]) + (a2[j] + a3[j]);
#pragma unroll
    for (int m = 8; m <= 32; m <<= 1) {
#pragma unroll
        for (int j = 0; j < 8; ++j) acc[j] += __shfl_xor(acc[j], m);
    }
    if (lane < 8) {
        float invd = 1.0f / fmaxf((float)(re - rs), 1.0f);
        h8 o;
#pragma unroll
        for (int j = 0; j < 8; ++j) o[j] = (_Float16)(acc[j] * invd);
        *reinterpret_cast<h8*>(agg + (size_t)wid * 64 + c8) = o;
    }
}

// ---------------- gather-mean D=32 (fp16 in/out): 16 rows per wave-load ----
__global__ __launch_bounds__(256) void k_gather32(const _Float16* __restrict__ z,
                                                  const int* __restrict__ rowptr,
                                                  const int* __restrict__ csr,
                                                  _Float16* __restrict__ agg) {
    int wid = (blockIdx.x * 256 + threadIdx.x) >> 6;  // node
    int lane = threadIdx.x & 63;
    if (wid >= N_NODES) return;
    int rs = (wid > 0) ? rowptr[wid - 1] : 0;
    int re = rowptr[wid];
    int sub = lane >> 2;
    int c8 = (lane & 3) * 8;
    float a0[8] = {0}, a1[8] = {0}, a2[8] = {0}, a3[8] = {0};
    for (int base = rs; base < re; base += 64) {
        int j = base + lane;
        int idx = (j < re) ? csr[j] : 0;
        int cnt = min(64, re - base);
        gadd<32>(a0, z, idx, 0 + sub, cnt, c8);
        if (16 < cnt) gadd<32>(a1, z, idx, 16 + sub, cnt, c8);
        if (32 < cnt) gadd<32>(a2, z, idx, 32 + sub, cnt, c8);
        if (48 < cnt) gadd<32>(a3, z, idx, 48 + sub, cnt, c8);
    }
    float acc[8];
#pragma unroll
    for (int j = 0; j < 8; ++j) acc[j] = (a0[j] + a1[j]) + (a2[j] + a3[j]);
#pragma unroll
    for (int m = 4; m <= 32; m <<= 1) {
#pragma unroll
        for (int j = 0; j < 8; ++j) acc[j] += __shfl_xor(acc[j], m);
    }
    if (lane < 4) {
        float invd = 1.0f / fmaxf((float)(re - rs), 1.0f);
        h8 o;
#pragma unroll
        for (int j = 0; j < 8; ++j) o[j] = (_Float16)(acc[j] * invd);
        *reinterpret_cast<h8*>(agg + (size_t)wid * 32 + c8) = o;
    }
}

// ------------- SAGE transform 64->64 via MFMA 16x16x32 f16 -----------------
template <bool RELU>
__global__ __launch_bounds__(256) void k_xform64m(const _Float16* __restrict__ x,
                                                  const _Float16* __restrict__ agg,
                                                  const float* __restrict__ Wl,
                                                  const float* __restrict__ b,
                                                  const float* __restrict__ Wr,
                                                  _Float16* __restrict__ out) {
    int lane = threadIdx.x & 63;
    int g = lane >> 4;   // k-group / row-group
    int r = lane & 15;   // A-row, C-col
    int wv = (blockIdx.x * 256 + threadIdx.x) >> 6;
    int nw = gridDim.x * 4;
    h8 wl[2][4], wr[2][4];
#pragma unroll
    for (int kt = 0; kt < 2; ++kt)
#pragma unroll
        for (int ct = 0; ct < 4; ++ct)
#pragma unroll
            for (int j = 0; j < 8; ++j) {
                int row = kt * 32 + g * 8 + j, col = ct * 16 + r;
                wl[kt][ct][j] = (_Float16)Wl[row * 64 + col];
                wr[kt][ct][j] = (_Float16)Wr[row * 64 + col];
            }
    float biasv[4];
#pragma unroll
    for (int ct = 0; ct < 4; ++ct) biasv[ct] = b[ct * 16 + r];
    for (int tile = wv; tile < N_NODES / 16; tile += nw) {
        int n0 = tile * 16;
        const h8* arow = reinterpret_cast<const h8*>(agg + (size_t)(n0 + r) * 64);
        const h8* xrow = reinterpret_cast<const h8*>(x + (size_t)(n0 + r) * 64);
        h8 aa0 = arow[g], aa1 = arow[4 + g];
        h8 ax0 = xrow[g], ax1 = xrow[4 + g];
        f32x4 acc[4];
#pragma unroll
        for (int ct = 0; ct < 4; ++ct) {
            acc[ct] = (f32x4){biasv[ct], biasv[ct], biasv[ct], biasv[ct]};
            acc[ct] = __builtin_amdgcn_mfma_f32_16x16x32_f16(aa0, wl[0][ct], acc[ct], 0, 0, 0);
            acc[ct] = __builtin_amdgcn_mfma_f32_16x16x32_f16(aa1, wl[1][ct], acc[ct], 0, 0, 0);
            acc[ct] = __builtin_amdgcn_mfma_f32_16x16x32_f16(ax0, wr[0][ct], acc[ct], 0, 0, 0);
            acc[ct] = __builtin_amdgcn_mfma_f32_16x16x32_f16(ax1, wr[1][ct], acc[ct], 0, 0, 0);
        }
#pragma unroll
        for (int reg = 0; reg < 4; ++reg) {
            float ss = acc[0][reg] * acc[0][reg] + acc[1][reg] * acc[1][reg] +
                       acc[2][reg] * acc[2][reg] + acc[3][reg] * acc[3][reg];
            ss += __shfl_xor(ss, 1);
            ss += __shfl_xor(ss, 2);
            ss += __shfl_xor(ss, 4);
            ss += __shfl_xor(ss, 8);
            float rinv = 1.0f / fmaxf(sqrtf(ss), 1e-12f);
            int row = n0 + g * 4 + reg;
#pragma unroll
            for (int ct = 0; ct < 4; ++ct) {
                float v = acc[ct][reg] * rinv;
                if (RELU) v = fmaxf(v, 0.0f);
                out[(size_t)row * 64 + ct * 16 + r] = (_Float16)v;
            }
        }
    }
}

// ------------- pre-transform layer3: z = x @ W3l (64 -> 32), fp16 ----------
__global__ __launch_bounds__(256, 2) void k_pretrans(const _Float16* __restrict__ x,
                                                     const float* __restrict__ W,
                                                     _Float16* __restrict__ z) {
    int lane = threadIdx.x & 63;
    int o = lane & 31;
    int h = lane >> 5;
    int wv = (blockIdx.x * 256 + threadIdx.x) >> 6;
    int nw = gridDim.x * 4;
    float wc[32];
#pragma unroll
    for (int j = 0; j < 32; ++j) wc[j] = W[(h * 32 + j) * 32 + o];
    for (int node = wv; node < N_NODES; node += nw) {
        float xr = (float)x[(size_t)node * 64 + lane];
        float acc = 0.f;
#pragma unroll
        for (int j = 0; j < 32; ++j) {
            float blo = bcast(xr, j);
            float bhi = bcast(xr, j + 32);
            acc = fmaf(h ? bhi : blo, wc[j], acc);
        }
        acc += __shfl_xor(acc, 32);
        if (lane < 32) z[(size_t)node * 32 + o] = (_Float16)acc;
    }
}

// ------------- layer3 finalize + fused column-sum ----------------
// out = normalize(agg32 + b + x @ W3r); colsum += sum over nodes of out.
__global__ __launch_bounds__(256, 2) void k_fin3(const _Float16* __restrict__ x,
                                                 const _Float16* __restrict__ agg32,
                                                 const float* __restrict__ b,
                                                 const float* __restrict__ Wr,
                                                 float* __restrict__ out,
                                                 float* __restrict__ colsum) {
    int lane = threadIdx.x & 63;
    int o = lane & 31;
    int h = lane >> 5;
    int wave = threadIdx.x >> 6;
    int wv = (blockIdx.x * 256 + threadIdx.x) >> 6;
    int nw = gridDim.x * 4;
    float wc[32];
#pragma unroll
    for (int j = 0; j < 32; ++j) wc[j] = Wr[(h * 32 + j) * 32 + o];
    float breg = b[o];
    float csacc = 0.f;
    for (int node = wv; node < N_NODES; node += nw) {
        float xr = (float)x[(size_t)node * 64 + lane];
        float acc = 0.f;
#pragma unroll
        for (int j = 0; j < 32; ++j) {
            float blo = bcast(xr, j);
            float bhi = bcast(xr, j + 32);
            acc = fmaf(h ? bhi : blo, wc[j], acc);
        }
        acc += __shfl_xor(acc, 32);
        float val = acc + (float)agg32[(size_t)node * 32 + o] + breg;
        float ss = val * val;
#pragma unroll
        for (int m = 16; m; m >>= 1) ss += __shfl_xor(ss, m);
        float ov = val / fmaxf(sqrtf(ss), 1e-12f);
        if (lane < 32) {
            out[(size_t)node * 32 + o] = ov;
            csacc += ov;
        }
    }
    __shared__ float sCS[4][32];
    if (lane < 32) sCS[wave][o] = csacc;
    __syncthreads();
    if (threadIdx.x < 32) {
        float v = sCS[0][threadIdx.x] + sCS[1][threadIdx.x] +
                  sCS[2][threadIdx.x] + sCS[3][threadIdx.x];
        atomicAdd(&colsum[threadIdx.x], v);
    }
}

// ------------- attention pool, register accumulation ----------------
__global__ __launch_bounds__(256) void k_attpool(const float* __restrict__ h,
                                                 const float* __restrict__ colsum,
                                                 const float* __restrict__ Watt,
                                                 float* __restrict__ pooled) {
    __shared__ float sC[32];
    __shared__ float sP[4][32];
    int t = threadIdx.x;
    if (t < 32) {
        float acc = 0.0f;
#pragma unroll
        for (int f = 0; f < 32; ++f)
            acc += (colsum[f] * (1.0f / N_NODES)) * Watt[f * 32 + t];
        sC[t] = tanhf(acc);
    }
    __syncthreads();
    float p[32];
#pragma unroll
    for (int f = 0; f < 32; ++f) p[f] = 0.f;
    int stride = gridDim.x * 256;
    for (int n = blockIdx.x * 256 + t; n < N_NODES; n += stride) {
        const f32x4* row = reinterpret_cast<const f32x4*>(h + (size_t)n * 32);
        f32x4 r[8];
        float dot = 0.0f;
#pragma unroll
        for (int q = 0; q < 8; ++q) {
            r[q] = row[q];
            dot += r[q][0] * sC[q * 4] + r[q][1] * sC[q * 4 + 1] +
                   r[q][2] * sC[q * 4 + 2] + r[q][3] * sC[q * 4 + 3];
        }
        float att = 1.0f / (1.0f + expf(-dot));
#pragma unroll
        for (int q = 0; q < 8; ++q) {
            p[q * 4 + 0] = fmaf(att, r[q][0], p[q * 4 + 0]);
            p[q * 4 + 1] = fmaf(att, r[q][1], p[q * 4 + 1]);
            p[q * 4 + 2] = fmaf(att, r[q][2], p[q * 4 + 2]);
            p[q * 4 + 3] = fmaf(att, r[q][3], p[q * 4 + 3]);
        }
    }
#pragma unroll
    for (int f = 0; f < 32; ++f) {
#pragma unroll
        for (int m = 1; m < 64; m <<= 1) p[f] += __shfl_xor(p[f], m);
    }
    int wave = t >> 6, lane = t & 63;
    if (lane == 0) {
#pragma unroll
        for (int f = 0; f < 32; ++f) sP[wave][f] = p[f];
    }
    __syncthreads();
    if (t < 32) {
        float v = sP[0][t] + sP[1][t] + sP[2][t] + sP[3][t];
        atomicAdd(&pooled[t], v);
    }
}

__global__ void k_head(const float* __restrict__ pooled,
                       const float* __restrict__ Wfc, const float* __restrict__ bfc,
                       const float* __restrict__ Ws, const float* __restrict__ bs,
                       float* __restrict__ out) {
    __shared__ float sH[16];
    int t = threadIdx.x;  // 64 threads
    if (t < 16) {
        float acc = bfc[t];
#pragma unroll
        for (int f = 0; f < 32; ++f) acc += pooled[f] * Wfc[f * 16 + t];
        sH[t] = fmaxf(acc, 0.0f);
    }
    __syncthreads();
    if (t == 0) {
        float s = bs[0];
#pragma unroll
        for (int j = 0; j < 16; ++j) s += sH[j] * Ws[j];
        out[0] = 1.0f / (1.0f + expf(-s));
    }
}

extern "C" void kernel_launch(void* const* d_in, const int* in_sizes, int n_in,
                              void* d_out, int out_size, void* d_ws, size_t ws_size,
                              hipStream_t stream) {
    const float* feat = (const float*)d_in[0];
    const int* ei = (const int*)d_in[1];
    const float* W1l = (const float*)d_in[2];
    const float* b1 = (const float*)d_in[3];
    const float* W1r = (const float*)d_in[4];
    const float* W2l = (const float*)d_in[5];
    const float* b2 = (const float*)d_in[6];
    const float* W2r = (const float*)d_in[7];
    const float* W3l = (const float*)d_in[8];
    const float* b3 = (const float*)d_in[9];
    const float* W3r = (const float*)d_in[10];
    const float* Watt = (const float*)d_in[11];
    const float* Wfc = (const float*)d_in[12];
    const float* bfc = (const float*)d_in[13];
    const float* Ws = (const float*)d_in[14];
    const float* bs = (const float*)d_in[15];
    float* out = (float*)d_out;

    // ---- workspace layout ----
    int* rowptr = (int*)d_ws;                    // 100000 (doubles as cursor)
    int* bsum = rowptr + 100000;                 // 128
    int* boff = bsum + 128;                      // 128
    int* counts = boff + 128;                    // 100000
    int* csr = counts + 100000;                  // 1,600,000
    _Float16* B1 = (_Float16*)(csr + N_EDGES);   // 6.4M halves (12.8 MB)
    _Float16* B2 = B1 + (size_t)N_NODES * 64;    // 6.4M halves
    _Float16* B3 = B2 + (size_t)N_NODES * 64;    // 6.4M halves
    float* h3 = (float*)(B3 + (size_t)N_NODES * 64);  // N*32 fp32
    float* colsum = h3 + (size_t)N_NODES * 32;        // 32
    float* pooled = colsum + 32;                      // 32

    // ---- CSR build + feat convert ----
    hipMemsetAsync(counts, 0, N_NODES * sizeof(int), stream);
    hipMemsetAsync(colsum, 0, 64 * sizeof(float), stream);
    k_cvt<<<3125, 256, 0, stream>>>(feat, B1);  // featH = B1
    k_count<<<(N_EDGES / 256) * 8, 256, 0, stream>>>(ei + N_EDGES, counts);
    k_scanA<<<SCAN_BLOCKS, 256, 0, stream>>>(counts, rowptr, bsum);
    k_scanB<<<1, 128, 0, stream>>>(bsum, boff);
    k_scanC<<<SCAN_BLOCKS, 256, 0, stream>>>(rowptr, boff);
    k_fill<<<(N_EDGES / 256) * 8, 256, 0, stream>>>(ei, rowptr, csr);
    // after k_fill: rowptr[t] == end of row t

    // ---- layer 1: gather featH -> B2; xform(featH,B2) -> h1 = B3 ----
    k_gather64<<<25000, 256, 0, stream>>>(B1, rowptr, csr, B2);
    k_xform64m<true><<<512, 256, 0, stream>>>(B1, B2, W1l, b1, W1r, B3);

    // ---- layer 2: gather h1 -> B2; xform(h1,B2) -> h2 = B1 ----
    k_gather64<<<25000, 256, 0, stream>>>(B3, rowptr, csr, B2);
    k_xform64m<true><<<512, 256, 0, stream>>>(B3, B2, W2l, b2, W2r, B1);

    // ---- layer 3: pretrans h2 -> z = B3lo; gather32 -> B3hi; fin3 -> h3 ----
    _Float16* z = B3;
    _Float16* agg32 = B3 + (size_t)N_NODES * 32;
    k_pretrans<<<1024, 256, 0, stream>>>(B1, W3l, z);
    k_gather32<<<25000, 256, 0, stream>>>(z, rowptr, csr, agg32);
    k_fin3<<<1024, 256, 0, stream>>>(B1, agg32, b3, W3r, h3, colsum);

    // ---- attention pooling + head ----
    k_attpool<<<391, 256, 0, stream>>>(h3, colsum, Watt, pooled);
    k_head<<<1, 64, 0, stream>>>(pooled, Wfc, bfc, Ws, bs, out);
}

// Round 10
// 463.974 us; speedup vs baseline: 8.4182x; 1.1294x over previous
//
#include <hip/hip_runtime.h>
#include <hip/hip_bf16.h>
#include <hip/hip_fp16.h>
#include <math.h>

#define N_NODES 100000
#define N_EDGES 1600000
#define SCAN_BLOCKS 98   // ceil(100000/1024)
#define XCD_RANGE 12500  // N_NODES / 8

typedef _Float16 h8 __attribute__((ext_vector_type(8)));
typedef float f32x4 __attribute__((ext_vector_type(4)));

__device__ __forceinline__ float bcast(float v, int l) {
    return __int_as_float(__builtin_amdgcn_readlane(__float_as_int(v), l));
}

// ---------------- fp32 -> fp16 convert (8 elems/thread) ----------------
__global__ __launch_bounds__(256) void k_cvt(const float* __restrict__ in,
                                             _Float16* __restrict__ out) {
    int i = blockIdx.x * 256 + threadIdx.x;  // 800000 threads
    const f32x4* p = reinterpret_cast<const f32x4*>(in) + (size_t)i * 2;
    f32x4 u = __builtin_nontemporal_load(p);
    f32x4 v = __builtin_nontemporal_load(p + 1);
    h8 o;
    o[0] = u[0]; o[1] = u[1]; o[2] = u[2]; o[3] = u[3];
    o[4] = v[0]; o[5] = v[1]; o[6] = v[2]; o[7] = v[3];
    *(reinterpret_cast<h8*>(out) + i) = o;
}

// ---------------- histogram of targets, XCD-partitioned ----------------
__global__ __launch_bounds__(256) void k_count(const int* __restrict__ tgt,
                                               int* __restrict__ counts) {
    int p = blockIdx.x & 7;
    int e = (blockIdx.x >> 3) * 256 + threadIdx.x;
    int t = __builtin_nontemporal_load(tgt + e);
    if ((unsigned)(t - p * XCD_RANGE) < XCD_RANGE) atomicAdd(&counts[t], 1);
}

// ---------------- block-local exclusive scan (1024/block) ----------------
__global__ __launch_bounds__(256) void k_scanA(const int* __restrict__ counts,
                                               int* __restrict__ rowptr,
                                               int* __restrict__ bsum) {
    int t = threadIdx.x;
    int base = blockIdx.x * 1024 + t * 4;
    int v0 = (base + 0 < N_NODES) ? counts[base + 0] : 0;
    int v1 = (base + 1 < N_NODES) ? counts[base + 1] : 0;
    int v2 = (base + 2 < N_NODES) ? counts[base + 2] : 0;
    int v3 = (base + 3 < N_NODES) ? counts[base + 3] : 0;
    int s = v0 + v1 + v2 + v3;
    __shared__ int sS[256];
    sS[t] = s;
    __syncthreads();
    for (int off = 1; off < 256; off <<= 1) {
        int add = (t >= off) ? sS[t - off] : 0;
        __syncthreads();
        sS[t] += add;
        __syncthreads();
    }
    int excl = sS[t] - s;
    if (t == 255) bsum[blockIdx.x] = sS[255];
    if (base + 0 < N_NODES) rowptr[base + 0] = excl;
    if (base + 1 < N_NODES) rowptr[base + 1] = excl + v0;
    if (base + 2 < N_NODES) rowptr[base + 2] = excl + v0 + v1;
    if (base + 3 < N_NODES) rowptr[base + 3] = excl + v0 + v1 + v2;
}

__global__ void k_scanB(const int* __restrict__ bsum, int* __restrict__ boff) {
    __shared__ int sD[128];
    int t = threadIdx.x;  // 128 threads
    int v = (t < SCAN_BLOCKS) ? bsum[t] : 0;
    sD[t] = v;
    __syncthreads();
    for (int off = 1; off < 128; off <<= 1) {
        int add = (t >= off) ? sD[t - off] : 0;
        __syncthreads();
        sD[t] += add;
        __syncthreads();
    }
    boff[t] = sD[t] - v;
}

__global__ __launch_bounds__(256) void k_scanC(int* __restrict__ rowptr,
                                               const int* __restrict__ boff) {
    int t = threadIdx.x;
    int base = blockIdx.x * 1024 + t * 4;
    int add = boff[blockIdx.x];
    if (base + 0 < N_NODES) rowptr[base + 0] += add;
    if (base + 1 < N_NODES) rowptr[base + 1] += add;
    if (base + 2 < N_NODES) rowptr[base + 2] += add;
    if (base + 3 < N_NODES) rowptr[base + 3] += add;
}

// ---------------- CSR fill, XCD-partitioned, NT edge reads ----------------
__global__ __launch_bounds__(256) void k_fill(const int* __restrict__ ei,
                                              int* __restrict__ rowptr,
                                              int* __restrict__ csr) {
    int p = blockIdx.x & 7;
    int e = (blockIdx.x >> 3) * 256 + threadIdx.x;
    int t = __builtin_nontemporal_load(ei + N_EDGES + e);
    if ((unsigned)(t - p * XCD_RANGE) < XCD_RANGE) {
        int s = __builtin_nontemporal_load(ei + e);
        int pos = atomicAdd(&rowptr[t], 1);
        csr[pos] = s;
    }
}

// ---------------- fp16 row accumulate: 8 rows per wave-load ----------------
template <int LD>
__device__ __forceinline__ void gadd(float (&A)[8], const _Float16* __restrict__ x,
                                     int idx, int n, int cnt, int c8) {
    int s = __shfl(idx, n);
    h8 v = *reinterpret_cast<const h8*>(x + (size_t)s * LD + c8);
    float m = (n < cnt) ? 1.0f : 0.0f;
#pragma unroll
    for (int j = 0; j < 8; ++j) A[j] = fmaf((float)v[j], m, A[j]);
}

// ---------------- gather-mean D=64 (fp16 in/out, fp32 accum) --------------
__global__ __launch_bounds__(256) void k_gather64(const _Float16* __restrict__ x,
                                                  const int* __restrict__ rowptr,
                                                  const int* __restrict__ csr,
                                                  _Float16* __restrict__ agg) {
    int wid = (blockIdx.x * 256 + threadIdx.x) >> 6;  // node
    int lane = threadIdx.x & 63;
    if (wid >= N_NODES) return;
    int rs = (wid > 0) ? rowptr[wid - 1] : 0;
    int re = rowptr[wid];
    int sub = lane >> 3;
    int c8 = (lane & 7) * 8;
    float a0[8] = {0}, a1[8] = {0}, a2[8] = {0}, a3[8] = {0};
    for (int base = rs; base < re; base += 64) {
        int j = base + lane;
        int idx = (j < re) ? csr[j] : 0;
        int cnt = min(64, re - base);
        {
            gadd<64>(a0, x, idx, 0 + sub, cnt, c8);
            gadd<64>(a1, x, idx, 8 + sub, cnt, c8);
        }
        if (16 < cnt) {
            gadd<64>(a2, x, idx, 16 + sub, cnt, c8);
            gadd<64>(a3, x, idx, 24 + sub, cnt, c8);
        }
        if (32 < cnt) {
            gadd<64>(a0, x, idx, 32 + sub, cnt, c8);
            gadd<64>(a1, x, idx, 40 + sub, cnt, c8);
        }
        if (48 < cnt) {
            gadd<64>(a2, x, idx, 48 + sub, cnt, c8);
            gadd<64>(a3, x, idx, 56 + sub, cnt, c8);
        }
    }
    float acc[8];
#pragma unroll
    for (int j = 0; j < 8; ++j) acc[j] = (a0[j] + a1[j]) + (a2[j] + a3[j]);
#pragma unroll
    for (int m = 8; m <= 32; m <<= 1) {
#pragma unroll
        for (int j = 0; j < 8; ++j) acc[j] += __shfl_xor(acc[j], m);
    }
    if (lane < 8) {
        float invd = 1.0f / fmaxf((float)(re - rs), 1.0f);
        h8 o;
#pragma unroll
        for (int j = 0; j < 8; ++j) o[j] = (_Float16)(acc[j] * invd);
        *reinterpret_cast<h8*>(agg + (size_t)wid * 64 + c8) = o;
    }
}

// ------------- SAGE transform 64->64 via MFMA 16x16x32 f16 (layer 1) -------
template <bool RELU>
__global__ __launch_bounds__(256) void k_xform64m(const _Float16* __restrict__ x,
                                                  const _Float16* __restrict__ agg,
                                                  const float* __restrict__ Wl,
                                                  const float* __restrict__ b,
                                                  const float* __restrict__ Wr,
                                                  _Float16* __restrict__ out) {
    int lane = threadIdx.x & 63;
    int g = lane >> 4;   // k-group / row-group
    int r = lane & 15;   // A-row, C-col
    int wv = (blockIdx.x * 256 + threadIdx.x) >> 6;
    int nw = gridDim.x * 4;
    h8 wl[2][4], wr[2][4];
#pragma unroll
    for (int kt = 0; kt < 2; ++kt)
#pragma unroll
        for (int ct = 0; ct < 4; ++ct)
#pragma unroll
            for (int j = 0; j < 8; ++j) {
                int row = kt * 32 + g * 8 + j, col = ct * 16 + r;
                wl[kt][ct][j] = (_Float16)Wl[row * 64 + col];
                wr[kt][ct][j] = (_Float16)Wr[row * 64 + col];
            }
    float biasv[4];
#pragma unroll
    for (int ct = 0; ct < 4; ++ct) biasv[ct] = b[ct * 16 + r];
    for (int tile = wv; tile < N_NODES / 16; tile += nw) {
        int n0 = tile * 16;
        const h8* arow = reinterpret_cast<const h8*>(agg + (size_t)(n0 + r) * 64);
        const h8* xrow = reinterpret_cast<const h8*>(x + (size_t)(n0 + r) * 64);
        h8 aa0 = arow[g], aa1 = arow[4 + g];
        h8 ax0 = xrow[g], ax1 = xrow[4 + g];
        f32x4 acc[4];
#pragma unroll
        for (int ct = 0; ct < 4; ++ct) {
            acc[ct] = (f32x4){biasv[ct], biasv[ct], biasv[ct], biasv[ct]};
            acc[ct] = __builtin_amdgcn_mfma_f32_16x16x32_f16(aa0, wl[0][ct], acc[ct], 0, 0, 0);
            acc[ct] = __builtin_amdgcn_mfma_f32_16x16x32_f16(aa1, wl[1][ct], acc[ct], 0, 0, 0);
            acc[ct] = __builtin_amdgcn_mfma_f32_16x16x32_f16(ax0, wr[0][ct], acc[ct], 0, 0, 0);
            acc[ct] = __builtin_amdgcn_mfma_f32_16x16x32_f16(ax1, wr[1][ct], acc[ct], 0, 0, 0);
        }
#pragma unroll
        for (int reg = 0; reg < 4; ++reg) {
            float ss = acc[0][reg] * acc[0][reg] + acc[1][reg] * acc[1][reg] +
                       acc[2][reg] * acc[2][reg] + acc[3][reg] * acc[3][reg];
            ss += __shfl_xor(ss, 1);
            ss += __shfl_xor(ss, 2);
            ss += __shfl_xor(ss, 4);
            ss += __shfl_xor(ss, 8);
            float rinv = 1.0f / fmaxf(sqrtf(ss), 1e-12f);
            int row = n0 + g * 4 + reg;
#pragma unroll
            for (int ct = 0; ct < 4; ++ct) {
                float v = acc[ct][reg] * rinv;
                if (RELU) v = fmaxf(v, 0.0f);
                out[(size_t)row * 64 + ct * 16 + r] = (_Float16)v;
            }
        }
    }
}

// ------------- layer-2 transform fused with layer-3 pre-transforms ---------
// h2 = relu(normalize(agg@W2l + b2 + x@W2r)) computed in registers, then
// round-tripped through per-wave LDS (stride 72 halves, 2-way-conflict-free)
// to A-fragments; emits z = h2@W3l and r3 = h2@W3r (both [N,32] fp16).
// h2 itself is never written.
__global__ __launch_bounds__(256) void k_xform64z(const _Float16* __restrict__ x,
                                                  const _Float16* __restrict__ agg,
                                                  const float* __restrict__ Wl,
                                                  const float* __restrict__ b,
                                                  const float* __restrict__ Wr,
                                                  const float* __restrict__ W3l,
                                                  const float* __restrict__ W3r,
                                                  _Float16* __restrict__ z,
                                                  _Float16* __restrict__ r3) {
    int lane = threadIdx.x & 63;
    int g = lane >> 4;
    int r = lane & 15;
    int wv4 = threadIdx.x >> 6;  // wave in block
    int wv = (blockIdx.x * 256 + threadIdx.x) >> 6;
    int nw = gridDim.x * 4;
    __shared__ _Float16 sT[4][16][72];
    h8 wl[2][4], wr[2][4];
#pragma unroll
    for (int kt = 0; kt < 2; ++kt)
#pragma unroll
        for (int ct = 0; ct < 4; ++ct)
#pragma unroll
            for (int j = 0; j < 8; ++j) {
                int row = kt * 32 + g * 8 + j, col = ct * 16 + r;
                wl[kt][ct][j] = (_Float16)Wl[row * 64 + col];
                wr[kt][ct][j] = (_Float16)Wr[row * 64 + col];
            }
    h8 wz[2][2], w3[2][2];
#pragma unroll
    for (int kt = 0; kt < 2; ++kt)
#pragma unroll
        for (int ct = 0; ct < 2; ++ct)
#pragma unroll
            for (int j = 0; j < 8; ++j) {
                int row = kt * 32 + g * 8 + j, col = ct * 16 + r;
                wz[kt][ct][j] = (_Float16)W3l[row * 32 + col];
                w3[kt][ct][j] = (_Float16)W3r[row * 32 + col];
            }
    float biasv[4];
#pragma unroll
    for (int ct = 0; ct < 4; ++ct) biasv[ct] = b[ct * 16 + r];
    for (int tile = wv; tile < N_NODES / 16; tile += nw) {
        int n0 = tile * 16;
        const h8* arow = reinterpret_cast<const h8*>(agg + (size_t)(n0 + r) * 64);
        const h8* xrow = reinterpret_cast<const h8*>(x + (size_t)(n0 + r) * 64);
        h8 aa0 = arow[g], aa1 = arow[4 + g];
        h8 ax0 = xrow[g], ax1 = xrow[4 + g];
        f32x4 acc[4];
#pragma unroll
        for (int ct = 0; ct < 4; ++ct) {
            acc[ct] = (f32x4){biasv[ct], biasv[ct], biasv[ct], biasv[ct]};
            acc[ct] = __builtin_amdgcn_mfma_f32_16x16x32_f16(aa0, wl[0][ct], acc[ct], 0, 0, 0);
            acc[ct] = __builtin_amdgcn_mfma_f32_16x16x32_f16(aa1, wl[1][ct], acc[ct], 0, 0, 0);
            acc[ct] = __builtin_amdgcn_mfma_f32_16x16x32_f16(ax0, wr[0][ct], acc[ct], 0, 0, 0);
            acc[ct] = __builtin_amdgcn_mfma_f32_16x16x32_f16(ax1, wr[1][ct], acc[ct], 0, 0, 0);
        }
        // normalize + relu -> h2 tile into LDS
#pragma unroll
        for (int reg = 0; reg < 4; ++reg) {
            float ss = acc[0][reg] * acc[0][reg] + acc[1][reg] * acc[1][reg] +
                       acc[2][reg] * acc[2][reg] + acc[3][reg] * acc[3][reg];
            ss += __shfl_xor(ss, 1);
            ss += __shfl_xor(ss, 2);
            ss += __shfl_xor(ss, 4);
            ss += __shfl_xor(ss, 8);
            float rinv = 1.0f / fmaxf(sqrtf(ss), 1e-12f);
            int row16 = g * 4 + reg;
#pragma unroll
            for (int ct = 0; ct < 4; ++ct) {
                float v = fmaxf(acc[ct][reg] * rinv, 0.0f);
                sT[wv4][row16][ct * 16 + r] = (_Float16)v;
            }
        }
        // re-fragment h2 as MFMA A-operand (same-wave LDS, no barrier needed)
        h8 ha0 = *reinterpret_cast<const h8*>(&sT[wv4][r][g * 8]);
        h8 ha1 = *reinterpret_cast<const h8*>(&sT[wv4][r][32 + g * 8]);
        f32x4 zacc[2], racc[2];
#pragma unroll
        for (int ct = 0; ct < 2; ++ct) {
            zacc[ct] = (f32x4){0, 0, 0, 0};
            zacc[ct] = __builtin_amdgcn_mfma_f32_16x16x32_f16(ha0, wz[0][ct], zacc[ct], 0, 0, 0);
            zacc[ct] = __builtin_amdgcn_mfma_f32_16x16x32_f16(ha1, wz[1][ct], zacc[ct], 0, 0, 0);
            racc[ct] = (f32x4){0, 0, 0, 0};
            racc[ct] = __builtin_amdgcn_mfma_f32_16x16x32_f16(ha0, w3[0][ct], racc[ct], 0, 0, 0);
            racc[ct] = __builtin_amdgcn_mfma_f32_16x16x32_f16(ha1, w3[1][ct], racc[ct], 0, 0, 0);
        }
#pragma unroll
        for (int reg = 0; reg < 4; ++reg) {
            int row = n0 + g * 4 + reg;
#pragma unroll
            for (int ct = 0; ct < 2; ++ct) {
                z[(size_t)row * 32 + ct * 16 + r] = (_Float16)zacc[ct][reg];
                r3[(size_t)row * 32 + ct * 16 + r] = (_Float16)racc[ct][reg];
            }
        }
    }
}

// ------------- gather-mean D=32 fused with layer-3 finalize ----------------
// h3[node] = normalize(mean_agg(z)[node] + b3 + r3[node])   (fp32 out)
__global__ __launch_bounds__(256) void k_g32fin(const _Float16* __restrict__ z,
                                                const int* __restrict__ rowptr,
                                                const int* __restrict__ csr,
                                                const _Float16* __restrict__ r3,
                                                const float* __restrict__ b3,
                                                float* __restrict__ h3) {
    int wid = (blockIdx.x * 256 + threadIdx.x) >> 6;  // node
    int lane = threadIdx.x & 63;
    if (wid >= N_NODES) return;
    int sub = lane >> 2;
    int c8 = (lane & 3) * 8;
    float bb[8];
#pragma unroll
    for (int j = 0; j < 8; ++j) bb[j] = b3[c8 + j];
    int rs = (wid > 0) ? rowptr[wid - 1] : 0;
    int re = rowptr[wid];
    float a0[8] = {0}, a1[8] = {0}, a2[8] = {0}, a3[8] = {0};
    for (int base = rs; base < re; base += 64) {
        int j = base + lane;
        int idx = (j < re) ? csr[j] : 0;
        int cnt = min(64, re - base);
        gadd<32>(a0, z, idx, 0 + sub, cnt, c8);
        if (16 < cnt) gadd<32>(a1, z, idx, 16 + sub, cnt, c8);
        if (32 < cnt) gadd<32>(a2, z, idx, 32 + sub, cnt, c8);
        if (48 < cnt) gadd<32>(a3, z, idx, 48 + sub, cnt, c8);
    }
    float acc[8];
#pragma unroll
    for (int j = 0; j < 8; ++j) acc[j] = (a0[j] + a1[j]) + (a2[j] + a3[j]);
#pragma unroll
    for (int m = 4; m <= 32; m <<= 1) {
#pragma unroll
        for (int j = 0; j < 8; ++j) acc[j] += __shfl_xor(acc[j], m);
    }
    // lanes 0-3 hold the full 32-wide row (8 cols each)
    float invd = 1.0f / fmaxf((float)(re - rs), 1.0f);
    h8 rr = (lane < 4) ? *reinterpret_cast<const h8*>(r3 + (size_t)wid * 32 + c8)
                       : (h8){0, 0, 0, 0, 0, 0, 0, 0};
    float val[8];
    float ss = 0.f;
#pragma unroll
    for (int j = 0; j < 8; ++j) {
        val[j] = fmaf(acc[j], invd, (float)rr[j] + bb[j]);
        ss = fmaf(val[j], val[j], ss);
    }
    ss += __shfl_xor(ss, 1);
    ss += __shfl_xor(ss, 2);
    if (lane < 4) {
        float rinv = 1.0f / fmaxf(sqrtf(ss), 1e-12f);
        f32x4 o0 = {val[0] * rinv, val[1] * rinv, val[2] * rinv, val[3] * rinv};
        f32x4 o1 = {val[4] * rinv, val[5] * rinv, val[6] * rinv, val[7] * rinv};
        f32x4* op = reinterpret_cast<f32x4*>(h3 + (size_t)wid * 32 + c8);
        op[0] = o0;
        op[1] = o1;
    }
}

// ------------- column sum of h3 [N,32] -------------
__global__ __launch_bounds__(256) void k_colsum(const float* __restrict__ h,
                                                float* __restrict__ colsum) {
    int gid = blockIdx.x * 256 + threadIdx.x;
    const int total = N_NODES * 32;
    const int stride = 1024 * 256;
    float s = 0.0f;
    for (int i = gid; i < total; i += stride) s += h[i];
    s += __shfl_xor(s, 32);
    __shared__ float sP[4][32];
    int wave = threadIdx.x >> 6, lane = threadIdx.x & 63;
    if (lane < 32) sP[wave][lane] = s;
    __syncthreads();
    if (threadIdx.x < 32) {
        float v = sP[0][threadIdx.x] + sP[1][threadIdx.x] + sP[2][threadIdx.x] +
                  sP[3][threadIdx.x];
        atomicAdd(&colsum[threadIdx.x], v);
    }
}

// ------------- attention pool, register accumulation ----------------
__global__ __launch_bounds__(256) void k_attpool(const float* __restrict__ h,
                                                 const float* __restrict__ colsum,
                                                 const float* __restrict__ Watt,
                                                 float* __restrict__ pooled) {
    __shared__ float sC[32];
    __shared__ float sP[4][32];
    int t = threadIdx.x;
    if (t < 32) {
        float acc = 0.0f;
#pragma unroll
        for (int f = 0; f < 32; ++f)
            acc += (colsum[f] * (1.0f / N_NODES)) * Watt[f * 32 + t];
        sC[t] = tanhf(acc);
    }
    __syncthreads();
    float p[32];
#pragma unroll
    for (int f = 0; f < 32; ++f) p[f] = 0.f;
    int stride = gridDim.x * 256;
    for (int n = blockIdx.x * 256 + t; n < N_NODES; n += stride) {
        const f32x4* row = reinterpret_cast<const f32x4*>(h + (size_t)n * 32);
        f32x4 r[8];
        float dot = 0.0f;
#pragma unroll
        for (int q = 0; q < 8; ++q) {
            r[q] = row[q];
            dot += r[q][0] * sC[q * 4] + r[q][1] * sC[q * 4 + 1] +
                   r[q][2] * sC[q * 4 + 2] + r[q][3] * sC[q * 4 + 3];
        }
        float att = 1.0f / (1.0f + expf(-dot));
#pragma unroll
        for (int q = 0; q < 8; ++q) {
            p[q * 4 + 0] = fmaf(att, r[q][0], p[q * 4 + 0]);
            p[q * 4 + 1] = fmaf(att, r[q][1], p[q * 4 + 1]);
            p[q * 4 + 2] = fmaf(att, r[q][2], p[q * 4 + 2]);
            p[q * 4 + 3] = fmaf(att, r[q][3], p[q * 4 + 3]);
        }
    }
#pragma unroll
    for (int f = 0; f < 32; ++f) {
#pragma unroll
        for (int m = 1; m < 64; m <<= 1) p[f] += __shfl_xor(p[f], m);
    }
    int wave = t >> 6, lane = t & 63;
    if (lane == 0) {
#pragma unroll
        for (int f = 0; f < 32; ++f) sP[wave][f] = p[f];
    }
    __syncthreads();
    if (t < 32) {
        float v = sP[0][t] + sP[1][t] + sP[2][t] + sP[3][t];
        atomicAdd(&pooled[t], v);
    }
}

__global__ void k_head(const float* __restrict__ pooled,
                       const float* __restrict__ Wfc, const float* __restrict__ bfc,
                       const float* __restrict__ Ws, const float* __restrict__ bs,
                       float* __restrict__ out) {
    __shared__ float sH[16];
    int t = threadIdx.x;  // 64 threads
    if (t < 16) {
        float acc = bfc[t];
#pragma unroll
        for (int f = 0; f < 32; ++f) acc += pooled[f] * Wfc[f * 16 + t];
        sH[t] = fmaxf(acc, 0.0f);
    }
    __syncthreads();
    if (t == 0) {
        float s = bs[0];
#pragma unroll
        for (int j = 0; j < 16; ++j) s += sH[j] * Ws[j];
        out[0] = 1.0f / (1.0f + expf(-s));
    }
}

extern "C" void kernel_launch(void* const* d_in, const int* in_sizes, int n_in,
                              void* d_out, int out_size, void* d_ws, size_t ws_size,
                              hipStream_t stream) {
    const float* feat = (const float*)d_in[0];
    const int* ei = (const int*)d_in[1];
    const float* W1l = (const float*)d_in[2];
    const float* b1 = (const float*)d_in[3];
    const float* W1r = (const float*)d_in[4];
    const float* W2l = (const float*)d_in[5];
    const float* b2 = (const float*)d_in[6];
    const float* W2r = (const float*)d_in[7];
    const float* W3l = (const float*)d_in[8];
    const float* b3 = (const float*)d_in[9];
    const float* W3r = (const float*)d_in[10];
    const float* Watt = (const float*)d_in[11];
    const float* Wfc = (const float*)d_in[12];
    const float* bfc = (const float*)d_in[13];
    const float* Ws = (const float*)d_in[14];
    const float* bs = (const float*)d_in[15];
    float* out = (float*)d_out;

    // ---- workspace layout ----
    int* rowptr = (int*)d_ws;                    // 100000 (doubles as cursor)
    int* bsum = rowptr + 100000;                 // 128
    int* boff = bsum + 128;                      // 128
    int* counts = boff + 128;                    // 100000
    int* csr = counts + 100000;                  // 1,600,000
    _Float16* B1 = (_Float16*)(csr + N_EDGES);   // 6.4M halves (12.8 MB)
    _Float16* B2 = B1 + (size_t)N_NODES * 64;    // 6.4M halves
    _Float16* B3 = B2 + (size_t)N_NODES * 64;    // 6.4M halves
    float* h3 = (float*)(B3 + (size_t)N_NODES * 64);  // N*32 fp32
    float* colsum = h3 + (size_t)N_NODES * 32;        // 32
    float* pooled = colsum + 32;                      // 32

    // ---- CSR build + feat convert ----
    hipMemsetAsync(counts, 0, N_NODES * sizeof(int), stream);
    hipMemsetAsync(colsum, 0, 64 * sizeof(float), stream);
    k_cvt<<<3125, 256, 0, stream>>>(feat, B1);  // featH = B1
    k_count<<<(N_EDGES / 256) * 8, 256, 0, stream>>>(ei + N_EDGES, counts);
    k_scanA<<<SCAN_BLOCKS, 256, 0, stream>>>(counts, rowptr, bsum);
    k_scanB<<<1, 128, 0, stream>>>(bsum, boff);
    k_scanC<<<SCAN_BLOCKS, 256, 0, stream>>>(rowptr, boff);
    k_fill<<<(N_EDGES / 256) * 8, 256, 0, stream>>>(ei, rowptr, csr);
    // after k_fill: rowptr[t] == end of row t

    // ---- layer 1: gather featH -> B2; xform(featH,B2) -> h1 = B3 ----
    k_gather64<<<25000, 256, 0, stream>>>(B1, rowptr, csr, B2);
    k_xform64m<true><<<512, 256, 0, stream>>>(B1, B2, W1l, b1, W1r, B3);

    // ---- layer 2 (+ fused layer-3 pretransforms):
    //      gather h1 -> B2; xform(h1,B2) -> z = B1lo, r3 = B1hi ----
    _Float16* z = B1;
    _Float16* r3 = B1 + (size_t)N_NODES * 32;
    k_gather64<<<25000, 256, 0, stream>>>(B3, rowptr, csr, B2);
    k_xform64z<<<512, 256, 0, stream>>>(B3, B2, W2l, b2, W2r, W3l, W3r, z, r3);

    // ---- layer 3: fused gather32 + finalize -> h3 (fp32) ----
    k_g32fin<<<25000, 256, 0, stream>>>(z, rowptr, csr, r3, b3, h3);

    // ---- attention pooling + head ----
    k_colsum<<<1024, 256, 0, stream>>>(h3, colsum);
    k_attpool<<<391, 256, 0, stream>>>(h3, colsum, Watt, pooled);
    k_head<<<1, 64, 0, stream>>>(pooled, Wfc, bfc, Ws, bs, out);
}